// Round 14
// baseline (9121.165 us; speedup 1.0000x reference)
//
#include <hip/hip_runtime.h>
#include <hip/hip_bf16.h>

// DGCNN forward on MI355X. B=8, N=2048, K=20.
// Round 14: DIST materialization eliminated. dist_sel computes the exact-fp32
// distance tile AND extracts per-(row, 128-slice) top-21 candidates in
// registers (16-lane shuffle butterflies, rescan-from-registers per the r6
// lesson), writing 336 (val,idx) pairs per query (44 MB/layer) instead of
// 8 KB raw distances (134 MB). knn_sel2 merges candidates. Distance values,
// chains and tie-breaks are bit-identical to round 13 (passed, 4.88e-4).

#define NEG_INF (-3.402823466e38f)
#define POS_INF (3.402823466e38f)

typedef __attribute__((ext_vector_type(8))) short short8;
typedef __attribute__((ext_vector_type(4))) float f32x4;

__device__ __forceinline__ float lk(float x) { return x > 0.f ? x : 0.2f * x; }

__device__ __forceinline__ bool pair_gt(float va, int ma, float vb, int mb) {
  return va > vb || (va == vb && ma < mb);
}

// ---------------- dtype probe: 1 = bf16, 0 = fp32 ----------------
__global__ void detect_dtype(const unsigned short* __restrict__ x16, int* __restrict__ flag) {
  if (threadIdx.x == 0 && blockIdx.x == 0) {
    int sane = 0;
    for (int i = 0; i < 64; ++i) {
      unsigned short u = x16[2 * i];
      int e = (u >> 7) & 0xff;
      if (e == 0 || (e >= 90 && e <= 140)) ++sane;
    }
    *flag = (sane >= 32) ? 1 : 0;
  }
}

// ---------------- batched convert-to-fp32 of all inputs ----------------
struct ConvTable {
  const void* src[30];
  float* dst[30];
  int n[30];
};

__global__ void conv_all(ConvTable t, const int* __restrict__ flag) {
  int e = blockIdx.y;
  int n = t.n[e];
  bool isbf = (*flag != 0);
  for (int i = blockIdx.x * 256 + threadIdx.x; i < n; i += gridDim.x * 256) {
    float v;
    if (isbf) v = __bfloat162float(((const __hip_bfloat16*)t.src[e])[i]);
    else      v = ((const float*)t.src[e])[i];
    t.dst[e][i] = v;
  }
}

__global__ void convf2b(const float* __restrict__ in, __hip_bfloat16* __restrict__ out, int n) {
  int i = blockIdx.x * 256 + threadIdx.x;
  if (i < n) out[i] = __float2bfloat16(in[i]);
}

// pad XF (BN x 3) into XFP (BN x 16), zeros beyond c=2. fmaf(0,0,s)=s keeps
// all distance/sq chains bitwise identical to the C=3 versions.
__global__ void xpad(const float* __restrict__ xf, float* __restrict__ xfp, int total) {
  int i = blockIdx.x * 256 + threadIdx.x;
  if (i >= total) return;
  int c = i & 15, n = i >> 4;
  xfp[i] = (c < 3) ? xf[n * 3 + c] : 0.f;
}

// ---------------- squared norms: SINGLE fmaf chain ascending c --------------
template <int C>
__global__ void sq_kernel(const float* __restrict__ xin, int ldx, float* __restrict__ sqb, int total) {
  int i = blockIdx.x * 256 + threadIdx.x;
  if (i >= total) return;
  const float* p = xin + (size_t)i * ldx;
  float s = 0.f;
  if (C == 3) {
    s = fmaf(p[0], p[0], s); s = fmaf(p[1], p[1], s); s = fmaf(p[2], p[2], s);
  } else {
#pragma unroll
    for (int c = 0; c < C; c += 4) {
      float4 xv = *(const float4*)(p + c);
      s = fmaf(xv.x, xv.x, s);
      s = fmaf(xv.y, xv.y, s);
      s = fmaf(xv.z, xv.z, s);
      s = fmaf(xv.w, xv.w, s);
    }
  }
  sqb[i] = s;
}

// ---------------- fused distance GEMM + per-slice top-21 extraction ---------
// 128x128 tile, 8x8 per thread, exact fp32 (chains match sq_kernel =>
// self-distance exactly 0). Row = 16 lanes x 8 register values; extraction =
// 21 rounds of width-16 xor butterfly + winner-lane register rescan.
// Output: cand[((b*N+q)*16 + slice)*21 + j] = (val, idx) in pair_gt order.
__global__ __launch_bounds__(256) void dist_sel(
    const float* __restrict__ xin, int ldx, const float* __restrict__ sqb,
    float2* __restrict__ cand, int N, int K) {
  __shared__ float As[16][132];
  __shared__ float Bs[16][132];
  const int tid = threadIdx.x;
  const int tx = tid & 15, ty = tid >> 4;
  const int mc0 = blockIdx.x * 128;
  const int qr0 = blockIdx.y * 128;
  const int b = blockIdx.z;
  float acc[8][8] = {};
  const int row = tid >> 1, kq = (tid & 1) * 8;
#pragma unroll 1
  for (int k0 = 0; k0 < K; k0 += 16) {
    float4 a0 = *(const float4*)&xin[(size_t)(b * N + qr0 + row) * ldx + k0 + kq];
    float4 a1 = *(const float4*)&xin[(size_t)(b * N + qr0 + row) * ldx + k0 + kq + 4];
    float4 b0 = *(const float4*)&xin[(size_t)(b * N + mc0 + row) * ldx + k0 + kq];
    float4 b1 = *(const float4*)&xin[(size_t)(b * N + mc0 + row) * ldx + k0 + kq + 4];
#pragma unroll
    for (int j = 0; j < 4; ++j) {
      As[kq + j][row] = (&a0.x)[j];
      As[kq + 4 + j][row] = (&a1.x)[j];
      Bs[kq + j][row] = (&b0.x)[j];
      Bs[kq + 4 + j][row] = (&b1.x)[j];
    }
    __syncthreads();
#pragma unroll
    for (int kk = 0; kk < 16; ++kk) {
      float av[8], bv[8];
      *(float4*)&av[0] = *(const float4*)&As[kk][8 * ty];
      *(float4*)&av[4] = *(const float4*)&As[kk][8 * ty + 4];
      *(float4*)&bv[0] = *(const float4*)&Bs[kk][4 * tx];
      *(float4*)&bv[4] = *(const float4*)&Bs[kk][64 + 4 * tx];
#pragma unroll
      for (int r = 0; r < 8; ++r)
#pragma unroll
        for (int c = 0; c < 8; ++c) acc[r][c] = fmaf(av[r], bv[c], acc[r][c]);
    }
    __syncthreads();
  }
  float sqq[8], sqm[8];
#pragma unroll
  for (int r = 0; r < 8; ++r) sqq[r] = sqb[b * N + qr0 + 8 * ty + r];
#pragma unroll
  for (int c = 0; c < 4; ++c) {
    sqm[c]     = sqb[b * N + mc0 + 4 * tx + c];
    sqm[c + 4] = sqb[b * N + mc0 + 64 + 4 * tx + c];
  }
#pragma unroll 1
  for (int r = 0; r < 8; ++r) {
    float rv[8];
    int rm[8];
#pragma unroll
    for (int c = 0; c < 4; ++c) {
      float t = sqq[r] - 2.f * acc[r][c];
      t = t + sqm[c];
      rv[c] = -t;
      rm[c] = mc0 + 4 * tx + c;
      float t2 = sqq[r] - 2.f * acc[r][c + 4];
      t2 = t2 + sqm[c + 4];
      rv[c + 4] = -t2;
      rm[c + 4] = mc0 + 64 + 4 * tx + c;
    }
    unsigned used = 0u;
    float bestv = NEG_INF;
    int bestm = 0x7fffffff;
#pragma unroll
    for (int c = 0; c < 8; ++c)
      if (pair_gt(rv[c], rm[c], bestv, bestm)) { bestv = rv[c]; bestm = rm[c]; }
    float s0v = 0.f, s1v = 0.f;
    int s0m = 0, s1m = 0;
#pragma unroll 1
    for (int sel = 0; sel < 21; ++sel) {
      float bv = bestv;
      int bm = bestm;
#pragma unroll
      for (int s = 1; s < 16; s <<= 1) {
        float ov = __shfl_xor(bv, s);
        int om = __shfl_xor(bm, s);
        if (pair_gt(ov, om, bv, bm)) { bv = ov; bm = om; }
      }
      if ((sel & 15) == tx) {
        if (sel < 16) { s0v = bv; s0m = bm; }
        else          { s1v = bv; s1m = bm; }
      }
      int col = bm - mc0;
      if (((col & 63) >> 2) == tx) {
        int cwin = (col >> 6) * 4 + (col & 3);
        used |= 1u << cwin;
        bestv = NEG_INF; bestm = 0x7fffffff;
#pragma unroll
        for (int c = 0; c < 8; ++c)
          if (!((used >> c) & 1u) && pair_gt(rv[c], rm[c], bestv, bestm)) {
            bestv = rv[c]; bestm = rm[c];
          }
      }
    }
    size_t cbase = (((size_t)(b * N + qr0 + 8 * ty + r)) * 16 + blockIdx.x) * 21;
    cand[cbase + tx] = make_float2(s0v, __int_as_float(s0m));
    if (tx < 5) cand[cbase + 16 + tx] = make_float2(s1v, __int_as_float(s1m));
  }
}

// ---------------- candidate merge: one wave per query over 336 pairs --------
__global__ __launch_bounds__(256) void knn_sel2(
    const float2* __restrict__ cand, int* __restrict__ idxout, int K) {
  const int lane = threadIdx.x & 63;
  const int wave = threadIdx.x >> 6;
  const int row = blockIdx.x * 4 + wave;     // b*N + q
  const float2* cq = cand + (size_t)row * 336;
  float cv[6];
  int cm[6];
#pragma unroll
  for (int i = 0; i < 6; ++i) {
    int j = lane + 64 * i;
    if (j < 336) {
      float2 p = cq[j];
      cv[i] = p.x; cm[i] = __float_as_int(p.y);
    } else {
      cv[i] = NEG_INF; cm[i] = 0x7fffffff;
    }
  }
  unsigned used = 0u;
  float bestv = NEG_INF;
  int bestm = 0x7fffffff;
#pragma unroll
  for (int i = 0; i < 6; ++i)
    if (pair_gt(cv[i], cm[i], bestv, bestm)) { bestv = cv[i]; bestm = cm[i]; }
#pragma unroll 1
  for (int sel = 0; sel <= K; ++sel) {
    float bv = bestv;
    int bm = bestm;
#pragma unroll
    for (int s = 1; s < 64; s <<= 1) {
      float ov = __shfl_xor(bv, s);
      int om = __shfl_xor(bm, s);
      if (pair_gt(ov, om, bv, bm)) { bv = ov; bm = om; }
    }
    if (sel > 0 && lane == 0)
      idxout[(size_t)row * K + (sel - 1)] = bm;
    if (bm == bestm) {   // owner lane (m unique across candidates)
#pragma unroll
      for (int i = 0; i < 6; ++i)
        if (cm[i] == bm) used |= 1u << i;
      bestv = NEG_INF; bestm = 0x7fffffff;
#pragma unroll
      for (int i = 0; i < 6; ++i)
        if (!((used >> i) & 1u) && pair_gt(cv[i], cm[i], bestv, bestm)) {
          bestv = cv[i]; bestm = cm[i];
        }
    }
  }
}

// ---------------- build [W2 ; W1-W2] from edge weight (O, 2C), fp32 ---------
__global__ void wcomb_build(const float* __restrict__ w, float* __restrict__ wc, int O, int C) {
  int i = blockIdx.x * 256 + threadIdx.x;
  if (i >= O * C) return;
  int o = i / C, c = i % C;
  float w1 = w[o * 2 * C + c];
  float w2 = w[o * 2 * C + C + c];
  wc[(size_t)o * C + c] = w2;                 // u rows
  wc[(size_t)(O + o) * C + c] = w1 - w2;      // v rows
}

// ---------------- fp32 C = A(MxK,lda) * B(NcxK)^T (UV gemms) ----------------
__global__ __launch_bounds__(256) void gemm_abt(
    const float* __restrict__ A, int lda, const float* __restrict__ Bm,
    float* __restrict__ Cm, int ldc, int M, int Nc, int K) {
  __shared__ float As[16][68];
  __shared__ float Bs[16][68];
  const int tid = threadIdx.x;
  const int tx = tid & 15, ty = tid >> 4;
  const int n0 = blockIdx.x * 64;
  const int m0 = blockIdx.y * 64;
  float acc[4][4] = {};
  const int nkt = (K + 15) / 16;
  for (int kt = 0; kt < nkt; ++kt) {
    int k0 = kt * 16;
#pragma unroll
    for (int ph = 0; ph < 4; ++ph) {
      int idx = tid + 256 * ph;
      int k = idx & 15, mr = idx >> 4;
      float v = 0.f;
      if (k0 + k < K) v = A[(size_t)(m0 + mr) * lda + k0 + k];
      As[k][mr] = v;
    }
#pragma unroll
    for (int ph = 0; ph < 4; ++ph) {
      int idx = tid + 256 * ph;
      int k = idx & 15, nr = idx >> 4;
      float v = 0.f;
      if (k0 + k < K) v = Bm[(size_t)(n0 + nr) * K + k0 + k];
      Bs[k][nr] = v;
    }
    __syncthreads();
#pragma unroll
    for (int kk = 0; kk < 16; ++kk) {
      float av[4], bv[4];
#pragma unroll
      for (int r = 0; r < 4; ++r) av[r] = As[kk][4 * ty + r];
#pragma unroll
      for (int c = 0; c < 4; ++c) bv[c] = Bs[kk][4 * tx + c];
#pragma unroll
      for (int r = 0; r < 4; ++r)
#pragma unroll
        for (int c = 0; c < 4; ++c) acc[r][c] = fmaf(av[r], bv[c], acc[r][c]);
    }
    __syncthreads();
  }
#pragma unroll
  for (int r = 0; r < 4; ++r) {
    float4 v = make_float4(acc[r][0], acc[r][1], acc[r][2], acc[r][3]);
    *(float4*)&Cm[(size_t)(m0 + 4 * ty + r) * ldc + n0 + 4 * tx] = v;
  }
}

// ---------------- MFMA bf16 GEMM: C = A(MxK) * B(NcxK)^T, fp32 out ----------
__global__ __launch_bounds__(256) void gemm_mfma_bt(
    const __hip_bfloat16* __restrict__ A, const __hip_bfloat16* __restrict__ Bm,
    float* __restrict__ Cm, int ldc, int M, int Nc, int K) {
  __shared__ __align__(16) __hip_bfloat16 Asm[128][40];
  __shared__ __align__(16) __hip_bfloat16 Bsm[128][40];
  const int tid = threadIdx.x;
  const int lane = tid & 63;
  const int wave = tid >> 6;
  const int wm = (wave >> 1) * 64;
  const int wn = (wave & 1) * 64;
  const int m0 = blockIdx.y * 128;
  const int n0 = blockIdx.x * 128;
  const int srow = tid >> 1, skq = (tid & 1) * 16;
  f32x4 acc[4][4] = {};
#pragma unroll 1
  for (int k0 = 0; k0 < K; k0 += 32) {
    short8 a0 = *(const short8*)&A[(size_t)(m0 + srow) * K + k0 + skq];
    short8 a1 = *(const short8*)&A[(size_t)(m0 + srow) * K + k0 + skq + 8];
    short8 b0 = *(const short8*)&Bm[(size_t)(n0 + srow) * K + k0 + skq];
    short8 b1 = *(const short8*)&Bm[(size_t)(n0 + srow) * K + k0 + skq + 8];
    *(short8*)&Asm[srow][skq] = a0;
    *(short8*)&Asm[srow][skq + 8] = a1;
    *(short8*)&Bsm[srow][skq] = b0;
    *(short8*)&Bsm[srow][skq + 8] = b1;
    __syncthreads();
    short8 af[4], bf_[4];
    const int fr = lane & 15, fq = (lane >> 4) * 8;
#pragma unroll
    for (int s = 0; s < 4; ++s)
      af[s] = *(const short8*)&Asm[wm + s * 16 + fr][fq];
#pragma unroll
    for (int t = 0; t < 4; ++t)
      bf_[t] = *(const short8*)&Bsm[wn + t * 16 + fr][fq];
#pragma unroll
    for (int s = 0; s < 4; ++s)
#pragma unroll
      for (int t = 0; t < 4; ++t)
        acc[s][t] = __builtin_amdgcn_mfma_f32_16x16x32_bf16(af[s], bf_[t], acc[s][t], 0, 0, 0);
    __syncthreads();
  }
  const int ccol = lane & 15, crow = (lane >> 4) * 4;
#pragma unroll
  for (int s = 0; s < 4; ++s)
#pragma unroll
    for (int t = 0; t < 4; ++t)
#pragma unroll
      for (int r = 0; r < 4; ++r) {
        int row = m0 + wm + s * 16 + crow + r;
        int col = n0 + wn + t * 16 + ccol;
        __builtin_nontemporal_store(acc[s][t][r], &Cm[(size_t)row * ldc + col]);
      }
}

// ---------------- edge conv pass1: h = v_n + u_m; stats + max/min over k ----
__global__ void edge_pass1(const float* __restrict__ uv, const int* __restrict__ idx,
                           float* __restrict__ hmax, float* __restrict__ hmin,
                           float* __restrict__ part, int N, int O, int K) {
  int b = blockIdx.y, n = blockIdx.x, o = threadIdx.x;
  size_t row = (size_t)b * N + n;
  const int twoO = 2 * O;
  float vv = uv[row * twoO + O + o];
  const int* ib = idx + row * K;
  float mx = NEG_INF, mn = POS_INF, s = 0.f, ss = 0.f;
  for (int k = 0; k < K; ++k) {
    int m = ib[k];
    float h = vv + uv[((size_t)b * N + m) * twoO + o];
    mx = fmaxf(mx, h); mn = fminf(mn, h);
    s += h; ss = fmaf(h, h, ss);
  }
  hmax[row * O + o] = mx;
  hmin[row * O + o] = mn;
  __shared__ float2 red[256];
  red[o] = make_float2(s, ss);
  __syncthreads();
  int gsz = O >> 2;
  int lane = o & (gsz - 1);
  for (int off = gsz >> 1; off > 0; off >>= 1) {
    if (lane < off) { red[o].x += red[o + off].x; red[o].y += red[o + off].y; }
    __syncthreads();
  }
  if (lane == 0) {
    int g = o / gsz;
    part[row * 8 + g * 2] = red[o].x;
    part[row * 8 + g * 2 + 1] = red[o].y;
  }
}

__global__ void stats_reduce(const float* __restrict__ part, float* __restrict__ st, int N) {
  int g = blockIdx.x, b = blockIdx.y, tid = threadIdx.x;
  float s = 0.f, ss = 0.f;
  for (int n = tid; n < N; n += 256) {
    size_t base = ((size_t)b * N + n) * 8 + g * 2;
    s += part[base]; ss += part[base + 1];
  }
  __shared__ float2 red[256];
  red[tid] = make_float2(s, ss);
  __syncthreads();
  for (int off = 128; off > 0; off >>= 1) {
    if (tid < off) { red[tid].x += red[tid + off].x; red[tid].y += red[tid + off].y; }
    __syncthreads();
  }
  if (tid == 0) { st[(b * 4 + g) * 2] = red[0].x; st[(b * 4 + g) * 2 + 1] = red[0].y; }
}

__global__ void edge_pass2(const float* __restrict__ hmax, const float* __restrict__ hmin,
                           const float* __restrict__ st,
                           const float* __restrict__ gw, const float* __restrict__ gb,
                           float* __restrict__ outbase, __hip_bfloat16* __restrict__ outbf,
                           int N, int O, int K, int coloff, int total) {
  int i = blockIdx.x * 256 + threadIdx.x;
  if (i >= total) return;
  int o = i % O;
  int n = (i / O) % N;
  int b = i / (O * N);
  int gsz = O >> 2;
  int g = o / gsz;
  float S = st[(b * 4 + g) * 2], SS = st[(b * 4 + g) * 2 + 1];
  float cnt = (float)N * (float)K * (float)gsz;
  float mean = S / cnt;
  float var = SS / cnt - mean * mean;
  float rs = rsqrtf(var + 1e-5f);
  float wf = gw[o], bf = gb[o];
  float Mv = (wf >= 0.f) ? hmax[i] : hmin[i];
  float val = lk((Mv - mean) * rs * wf + bf);
  size_t pos = ((size_t)b * N + n) * 512 + coloff + o;
  outbase[pos] = val;
  outbf[pos] = __float2bfloat16(val);
}

// ---------------- gn_seq stats: two-phase ----------------
__global__ void seq_part(const float* __restrict__ h, float4* __restrict__ pq, int N) {
  int b = blockIdx.y, chunk = blockIdx.z;
  int c = blockIdx.x * 256 + threadIdx.x;
  float mx = NEG_INF, mn = POS_INF, s = 0.f, ss = 0.f;
  int nbeg = chunk * 128;
#pragma unroll 1
  for (int n = nbeg; n < nbeg + 128; ++n) {
    float v = __builtin_nontemporal_load(&h[((size_t)b * N + n) * 1024 + c]);
    mx = fmaxf(mx, v); mn = fminf(mn, v);
    s += v; ss = fmaf(v, v, ss);
  }
  pq[((size_t)(b * 16 + chunk)) * 1024 + c] = make_float4(mx, mn, s, ss);
}

__global__ void seq_fin(const float4* __restrict__ pq, float* __restrict__ st16,
                        float* __restrict__ maxv, float* __restrict__ minv) {
  int b = blockIdx.y;
  int tid = threadIdx.x;
  int c = blockIdx.x * 256 + tid;
  float mx = NEG_INF, mn = POS_INF, s = 0.f, ss = 0.f;
#pragma unroll
  for (int ch = 0; ch < 16; ++ch) {
    float4 p = pq[((size_t)(b * 16 + ch)) * 1024 + c];
    mx = fmaxf(mx, p.x); mn = fminf(mn, p.y);
    s += p.z; ss += p.w;
  }
  maxv[b * 1024 + c] = mx;
  minv[b * 1024 + c] = mn;
  __shared__ float2 red[256];
  red[tid] = make_float2(s, ss);
  __syncthreads();
  int lane = tid & 63;
  for (int off = 32; off > 0; off >>= 1) {
    if (lane < off) { red[tid].x += red[tid + off].x; red[tid].y += red[tid + off].y; }
    __syncthreads();
  }
  if (lane == 0) {
    int g = c >> 6;
    st16[(b * 16 + g) * 2] = red[tid].x;
    st16[(b * 16 + g) * 2 + 1] = red[tid].y;
  }
}

__global__ void seq_apply(const float* __restrict__ st16, const float* __restrict__ maxv,
                          const float* __restrict__ minv, const float* __restrict__ gw,
                          const float* __restrict__ gb, float* __restrict__ g, int N) {
  int i = blockIdx.x * 256 + threadIdx.x;
  if (i >= 8 * 1024) return;
  int b = i >> 10, c = i & 1023;
  int grp = c >> 6;
  float S = st16[(b * 16 + grp) * 2], SS = st16[(b * 16 + grp) * 2 + 1];
  float cnt = (float)N * 64.f;
  float mean = S / cnt;
  float var = SS / cnt - mean * mean;
  float rs = rsqrtf(var + 1e-5f);
  float wf = gw[c], bf = gb[c];
  float Mv = (wf >= 0.f) ? maxv[i] : minv[i];
  g[i] = lk((Mv - mean) * rs * wf + bf);
}

// ---------------- fused MLP head: one block per batch ----------------
__device__ void block_fc(const float* in, int Cin, int Cout,
                         const float* __restrict__ w, const float* __restrict__ bias,
                         float* z) {
  int tid = threadIdx.x;
  for (int o = tid; o < Cout; o += 256) {
    const float* wr = w + (size_t)o * Cin;
    float acc = 0.f;
    for (int c = 0; c < Cin; c += 4) {
      float4 w4 = *(const float4*)(wr + c);
      acc = fmaf(in[c], w4.x, acc);
      acc = fmaf(in[c + 1], w4.y, acc);
      acc = fmaf(in[c + 2], w4.z, acc);
      acc = fmaf(in[c + 3], w4.w, acc);
    }
    z[o] = acc + bias[o];
  }
  __syncthreads();
}

__device__ void block_ln_leaky(const float* z, int Cn, const float* __restrict__ w,
                               const float* __restrict__ bias, float* out, float2* red) {
  int tid = threadIdx.x;
  float s = 0.f, ss = 0.f;
  for (int o = tid; o < Cn; o += 256) { float v = z[o]; s += v; ss = fmaf(v, v, ss); }
  red[tid] = make_float2(s, ss);
  __syncthreads();
  for (int off = 128; off > 0; off >>= 1) {
    if (tid < off) { red[tid].x += red[tid + off].x; red[tid].y += red[tid + off].y; }
    __syncthreads();
  }
  float mean = red[0].x / Cn;
  float var = red[0].y / Cn - mean * mean;
  float rs = rsqrtf(var + 1e-5f);
  __syncthreads();
  for (int o = tid; o < Cn; o += 256) out[o] = lk((z[o] - mean) * rs * w[o] + bias[o]);
  __syncthreads();
}

__global__ __launch_bounds__(256) void mlp_head(
    const float* __restrict__ gvec,
    const float* __restrict__ fc1w, const float* __restrict__ fc1b,
    const float* __restrict__ ln1w, const float* __restrict__ ln1b,
    const float* __restrict__ fc2w, const float* __restrict__ fc2b,
    const float* __restrict__ ln2w, const float* __restrict__ ln2b,
    const float* __restrict__ fc3w, const float* __restrict__ fc3b,
    const float* __restrict__ ln3w, const float* __restrict__ ln3b,
    const float* __restrict__ fc4w, const float* __restrict__ fc4b,
    void* __restrict__ out, const int* __restrict__ flag) {
  __shared__ float ping[1024];
  __shared__ float pong[512];
  __shared__ float2 red[256];
  const int b = blockIdx.x, tid = threadIdx.x;
  for (int i = tid; i < 1024; i += 256) ping[i] = gvec[b * 1024 + i];
  __syncthreads();
  block_fc(ping, 1024, 512, fc1w, fc1b, pong);
  block_ln_leaky(pong, 512, ln1w, ln1b, ping, red);
  block_fc(ping, 512, 256, fc2w, fc2b, pong);
  block_ln_leaky(pong, 256, ln2w, ln2b, ping, red);
  block_fc(ping, 256, 64, fc3w, fc3b, pong);
  block_ln_leaky(pong, 64, ln3w, ln3b, ping, red);
  if (tid < 2) {
    float acc = 0.f;
    for (int c = 0; c < 64; ++c) acc = fmaf(ping[c], fc4w[tid * 64 + c], acc);
    acc += fc4b[tid];
    if (*flag) ((__hip_bfloat16*)out)[b * 2 + tid] = __float2bfloat16(acc);
    else       ((float*)out)[b * 2 + tid] = acc;
  }
}

// ---------------- host-side dispatch helpers -----------------------
static void launch_sq(int C, const float* xin, int ldx, float* sqb, int BN, hipStream_t s) {
  dim3 g((BN + 255) / 256);
  if (C == 3)       sq_kernel<3><<<g, 256, 0, s>>>(xin, ldx, sqb, BN);
  else if (C == 64) sq_kernel<64><<<g, 256, 0, s>>>(xin, ldx, sqb, BN);
  else              sq_kernel<128><<<g, 256, 0, s>>>(xin, ldx, sqb, BN);
}

extern "C" void kernel_launch(void* const* d_in, const int* in_sizes, int n_in,
                              void* d_out, int out_size, void* d_ws, size_t ws_size,
                              hipStream_t stream) {
  (void)out_size; (void)ws_size;
  const int B = 8, N = 2048, KNN = 20;
  const int BN = B * N;

  float* base = (float*)d_ws;
  size_t off = 0;
  auto alloc = [&](size_t nf) { float* p = base + off; off += nf; return p; };

  int*   FLAG  = (int*)alloc(16);
  float* XF    = alloc((size_t)BN * 3);
  float* XFP   = alloc((size_t)BN * 16);
  float* HCAT  = alloc((size_t)BN * 512);
  float* DISTB = alloc((size_t)BN * 2048);   // UV|HMAX|HMIN | CAND | H1024
  float* UV    = DISTB;                       // BN*512
  float* HMAX  = DISTB + (size_t)BN * 512;    // BN*256
  float* HMIN  = DISTB + (size_t)BN * 768;    // BN*256
  float* H1024 = DISTB + (size_t)BN * 1024;   // BN*1024 (after layer loop)
  float2* CAND = (float2*)(DISTB + (size_t)BN * 1024);  // BN*336 float2 (44MB) during layers
  float* SQB   = alloc(BN);
  float* WCOMB = alloc((size_t)512 * 128);
  float* PART  = alloc((size_t)BN * 8);
  float* ST4   = alloc(64);
  float* ST16  = alloc(512);
  float* PQST  = alloc((size_t)8 * 16 * 1024 * 4);
  float* MAXV  = alloc(8 * 1024);
  float* MINV  = alloc(8 * 1024);
  float* GVEC  = alloc(8 * 1024);
  int*   IDX = (int*)alloc((size_t)BN * KNN);
  __hip_bfloat16* HCATBF = (__hip_bfloat16*)alloc((size_t)BN * 256);  // BN*512 bf16
  __hip_bfloat16* WMBF   = (__hip_bfloat16*)alloc(262144);            // 1024*512 bf16

  // converted fp32 weights
  ConvTable ct;
  float* conv_dst[30];
  for (int i = 0; i < 30; ++i) {
    int n = in_sizes[i];
    conv_dst[i] = alloc((size_t)((n + 15) & ~15));
    ct.src[i] = d_in[i];
    ct.dst[i] = conv_dst[i];
    ct.n[i] = n;
  }
  ct.dst[0] = XF; ct.n[0] = BN * 3;

  const float* W_[4]  = {conv_dst[1], conv_dst[4], conv_dst[7], conv_dst[10]};
  const float* GW_[4] = {conv_dst[2], conv_dst[5], conv_dst[8], conv_dst[11]};
  const float* GB_[4] = {conv_dst[3], conv_dst[6], conv_dst[9], conv_dst[12]};
  const float* WM = conv_dst[13];
  const float* GMW = conv_dst[14], *GMB = conv_dst[15];
  const float* FC1W = conv_dst[16], *FC1B = conv_dst[17], *LN1W = conv_dst[18], *LN1B = conv_dst[19];
  const float* FC2W = conv_dst[20], *FC2B = conv_dst[21], *LN2W = conv_dst[22], *LN2B = conv_dst[23];
  const float* FC3W = conv_dst[24], *FC3B = conv_dst[25], *LN3W = conv_dst[26], *LN3B = conv_dst[27];
  const float* FC4W = conv_dst[28], *FC4B = conv_dst[29];

  detect_dtype<<<dim3(1), 64, 0, stream>>>((const unsigned short*)d_in[0], FLAG);
  conv_all<<<dim3(256, 30), 256, 0, stream>>>(ct, FLAG);
  convf2b<<<dim3(2048), 256, 0, stream>>>(WM, WMBF, 1024 * 512);
  xpad<<<dim3((BN * 16 + 255) / 256), 256, 0, stream>>>(XF, XFP, BN * 16);

  const int Cs[4]     = {3, 64, 64, 128};
  const int Os[4]     = {64, 64, 128, 256};
  const int incol[4]  = {0, 0, 64, 128};
  const int outcol[4] = {0, 64, 128, 256};

  for (int l = 0; l < 4; ++l) {
    const int C = Cs[l], O = Os[l], twoO = 2 * O;
    const float* xin = (l == 0) ? XF : (HCAT + incol[l]);
    const int ldx = (l == 0) ? 3 : 512;

    launch_sq(C, xin, ldx, SQB, BN, stream);
    if (l == 0)
      dist_sel<<<dim3(16, 16, 8), 256, 0, stream>>>(XFP, 16, SQB, CAND, N, 16);
    else
      dist_sel<<<dim3(16, 16, 8), 256, 0, stream>>>(xin, 512, SQB, CAND, N, C);
    knn_sel2<<<dim3(BN / 4), 256, 0, stream>>>(CAND, IDX, KNN);
    wcomb_build<<<dim3((O * C + 255) / 256), 256, 0, stream>>>(W_[l], WCOMB, O, C);
    gemm_abt<<<dim3(twoO / 64, BN / 64), 256, 0, stream>>>(xin, ldx, WCOMB, UV, twoO, BN, twoO, C);
    edge_pass1<<<dim3(N, B), O, 0, stream>>>(UV, IDX, HMAX, HMIN, PART, N, O, KNN);
    stats_reduce<<<dim3(4, B), 256, 0, stream>>>(PART, ST4, N);
    int tot = BN * O;
    edge_pass2<<<dim3((tot + 255) / 256), 256, 0, stream>>>(HMAX, HMIN, ST4, GW_[l], GB_[l],
                                                            HCAT, HCATBF, N, O, KNN, outcol[l], tot);
  }

  gemm_mfma_bt<<<dim3(1024 / 128, BN / 128), 256, 0, stream>>>(HCATBF, WMBF, H1024, 1024, BN, 1024, 512);
  seq_part<<<dim3(4, 8, 16), 256, 0, stream>>>(H1024, (float4*)PQST, N);
  seq_fin<<<dim3(4, 8), 256, 0, stream>>>((const float4*)PQST, ST16, MAXV, MINV);
  seq_apply<<<dim3(32), 256, 0, stream>>>(ST16, MAXV, MINV, GMW, GMB, GVEC, N);

  mlp_head<<<dim3(8), 256, 0, stream>>>(GVEC, FC1W, FC1B, LN1W, LN1B,
                                        FC2W, FC2B, LN2W, LN2B,
                                        FC3W, FC3B, LN3W, LN3B,
                                        FC4W, FC4B, d_out, FLAG);
}

// Round 15
// 2208.906 us; speedup vs baseline: 4.1293x; 4.1293x over previous
//
#include <hip/hip_runtime.h>
#include <hip/hip_bf16.h>

// DGCNN forward on MI355X. B=8, N=2048, K=20.
// Round 15 (= round-14 intent, codegen fixed): the r-loop over accumulator
// rows in dist_sel's epilogue is now FULLY UNROLLED -- r14's `#pragma unroll 1`
// made acc[r][c] dynamically indexed, demoting acc[8][8] to scratch
// (10.7 GB spill traffic/dispatch, 52 VGPR, 8x regression). Values, chains
// and tie-breaks remain bit-identical to round 13 (passed, 4.88e-4).

#define NEG_INF (-3.402823466e38f)
#define POS_INF (3.402823466e38f)

typedef __attribute__((ext_vector_type(8))) short short8;
typedef __attribute__((ext_vector_type(4))) float f32x4;

__device__ __forceinline__ float lk(float x) { return x > 0.f ? x : 0.2f * x; }

__device__ __forceinline__ bool pair_gt(float va, int ma, float vb, int mb) {
  return va > vb || (va == vb && ma < mb);
}

// ---------------- dtype probe: 1 = bf16, 0 = fp32 ----------------
__global__ void detect_dtype(const unsigned short* __restrict__ x16, int* __restrict__ flag) {
  if (threadIdx.x == 0 && blockIdx.x == 0) {
    int sane = 0;
    for (int i = 0; i < 64; ++i) {
      unsigned short u = x16[2 * i];
      int e = (u >> 7) & 0xff;
      if (e == 0 || (e >= 90 && e <= 140)) ++sane;
    }
    *flag = (sane >= 32) ? 1 : 0;
  }
}

// ---------------- batched convert-to-fp32 of all inputs ----------------
struct ConvTable {
  const void* src[30];
  float* dst[30];
  int n[30];
};

__global__ void conv_all(ConvTable t, const int* __restrict__ flag) {
  int e = blockIdx.y;
  int n = t.n[e];
  bool isbf = (*flag != 0);
  for (int i = blockIdx.x * 256 + threadIdx.x; i < n; i += gridDim.x * 256) {
    float v;
    if (isbf) v = __bfloat162float(((const __hip_bfloat16*)t.src[e])[i]);
    else      v = ((const float*)t.src[e])[i];
    t.dst[e][i] = v;
  }
}

__global__ void convf2b(const float* __restrict__ in, __hip_bfloat16* __restrict__ out, int n) {
  int i = blockIdx.x * 256 + threadIdx.x;
  if (i < n) out[i] = __float2bfloat16(in[i]);
}

// pad XF (BN x 3) into XFP (BN x 16), zeros beyond c=2. fmaf(0,0,s)=s keeps
// all distance/sq chains bitwise identical to the C=3 versions.
__global__ void xpad(const float* __restrict__ xf, float* __restrict__ xfp, int total) {
  int i = blockIdx.x * 256 + threadIdx.x;
  if (i >= total) return;
  int c = i & 15, n = i >> 4;
  xfp[i] = (c < 3) ? xf[n * 3 + c] : 0.f;
}

// ---------------- squared norms: SINGLE fmaf chain ascending c --------------
template <int C>
__global__ void sq_kernel(const float* __restrict__ xin, int ldx, float* __restrict__ sqb, int total) {
  int i = blockIdx.x * 256 + threadIdx.x;
  if (i >= total) return;
  const float* p = xin + (size_t)i * ldx;
  float s = 0.f;
  if (C == 3) {
    s = fmaf(p[0], p[0], s); s = fmaf(p[1], p[1], s); s = fmaf(p[2], p[2], s);
  } else {
#pragma unroll
    for (int c = 0; c < C; c += 4) {
      float4 xv = *(const float4*)(p + c);
      s = fmaf(xv.x, xv.x, s);
      s = fmaf(xv.y, xv.y, s);
      s = fmaf(xv.z, xv.z, s);
      s = fmaf(xv.w, xv.w, s);
    }
  }
  sqb[i] = s;
}

// ---------------- fused distance GEMM + per-slice top-21 extraction ---------
// 128x128 tile, 8x8 per thread, exact fp32 (chains match sq_kernel =>
// self-distance exactly 0). Row = 16 lanes x 8 register values; extraction =
// 21 rounds of width-16 xor butterfly + winner-lane register rescan.
// Output: cand[((b*N+q)*16 + slice)*21 + j] = (val, idx) in pair_gt order.
__global__ __launch_bounds__(256, 4) void dist_sel(
    const float* __restrict__ xin, int ldx, const float* __restrict__ sqb,
    float2* __restrict__ cand, int N, int K) {
  __shared__ float As[16][132];
  __shared__ float Bs[16][132];
  const int tid = threadIdx.x;
  const int tx = tid & 15, ty = tid >> 4;
  const int mc0 = blockIdx.x * 128;
  const int qr0 = blockIdx.y * 128;
  const int b = blockIdx.z;
  float acc[8][8] = {};
  const int row = tid >> 1, kq = (tid & 1) * 8;
#pragma unroll 1
  for (int k0 = 0; k0 < K; k0 += 16) {
    float4 a0 = *(const float4*)&xin[(size_t)(b * N + qr0 + row) * ldx + k0 + kq];
    float4 a1 = *(const float4*)&xin[(size_t)(b * N + qr0 + row) * ldx + k0 + kq + 4];
    float4 b0 = *(const float4*)&xin[(size_t)(b * N + mc0 + row) * ldx + k0 + kq];
    float4 b1 = *(const float4*)&xin[(size_t)(b * N + mc0 + row) * ldx + k0 + kq + 4];
#pragma unroll
    for (int j = 0; j < 4; ++j) {
      As[kq + j][row] = (&a0.x)[j];
      As[kq + 4 + j][row] = (&a1.x)[j];
      Bs[kq + j][row] = (&b0.x)[j];
      Bs[kq + 4 + j][row] = (&b1.x)[j];
    }
    __syncthreads();
#pragma unroll
    for (int kk = 0; kk < 16; ++kk) {
      float av[8], bv[8];
      *(float4*)&av[0] = *(const float4*)&As[kk][8 * ty];
      *(float4*)&av[4] = *(const float4*)&As[kk][8 * ty + 4];
      *(float4*)&bv[0] = *(const float4*)&Bs[kk][4 * tx];
      *(float4*)&bv[4] = *(const float4*)&Bs[kk][64 + 4 * tx];
#pragma unroll
      for (int r = 0; r < 8; ++r)
#pragma unroll
        for (int c = 0; c < 8; ++c) acc[r][c] = fmaf(av[r], bv[c], acc[r][c]);
    }
    __syncthreads();
  }
  float sqq[8], sqm[8];
#pragma unroll
  for (int r = 0; r < 8; ++r) sqq[r] = sqb[b * N + qr0 + 8 * ty + r];
#pragma unroll
  for (int c = 0; c < 4; ++c) {
    sqm[c]     = sqb[b * N + mc0 + 4 * tx + c];
    sqm[c + 4] = sqb[b * N + mc0 + 64 + 4 * tx + c];
  }
  // FULLY unrolled over r: acc indices must be compile-time constants so the
  // accumulator stays in VGPRs (r14 lesson: unroll-1 here => scratch spill).
#pragma unroll
  for (int r = 0; r < 8; ++r) {
    float rv[8];
    int rm[8];
#pragma unroll
    for (int c = 0; c < 4; ++c) {
      float t = sqq[r] - 2.f * acc[r][c];
      t = t + sqm[c];
      rv[c] = -t;
      rm[c] = mc0 + 4 * tx + c;
      float t2 = sqq[r] - 2.f * acc[r][c + 4];
      t2 = t2 + sqm[c + 4];
      rv[c + 4] = -t2;
      rm[c + 4] = mc0 + 64 + 4 * tx + c;
    }
    unsigned used = 0u;
    float bestv = NEG_INF;
    int bestm = 0x7fffffff;
#pragma unroll
    for (int c = 0; c < 8; ++c)
      if (pair_gt(rv[c], rm[c], bestv, bestm)) { bestv = rv[c]; bestm = rm[c]; }
    float s0v = 0.f, s1v = 0.f;
    int s0m = 0, s1m = 0;
#pragma unroll 1
    for (int sel = 0; sel < 21; ++sel) {
      float bv = bestv;
      int bm = bestm;
#pragma unroll
      for (int s = 1; s < 16; s <<= 1) {
        float ov = __shfl_xor(bv, s);
        int om = __shfl_xor(bm, s);
        if (pair_gt(ov, om, bv, bm)) { bv = ov; bm = om; }
      }
      if ((sel & 15) == tx) {
        if (sel < 16) { s0v = bv; s0m = bm; }
        else          { s1v = bv; s1m = bm; }
      }
      int col = bm - mc0;
      if (((col & 63) >> 2) == tx) {
        int cwin = (col >> 6) * 4 + (col & 3);
        used |= 1u << cwin;
        bestv = NEG_INF; bestm = 0x7fffffff;
#pragma unroll
        for (int c = 0; c < 8; ++c)
          if (!((used >> c) & 1u) && pair_gt(rv[c], rm[c], bestv, bestm)) {
            bestv = rv[c]; bestm = rm[c];
          }
      }
    }
    size_t cbase = (((size_t)(b * N + qr0 + 8 * ty + r)) * 16 + blockIdx.x) * 21;
    cand[cbase + tx] = make_float2(s0v, __int_as_float(s0m));
    if (tx < 5) cand[cbase + 16 + tx] = make_float2(s1v, __int_as_float(s1m));
  }
}

// ---------------- candidate merge: one wave per query over 336 pairs --------
__global__ __launch_bounds__(256) void knn_sel2(
    const float2* __restrict__ cand, int* __restrict__ idxout, int K) {
  const int lane = threadIdx.x & 63;
  const int wave = threadIdx.x >> 6;
  const int row = blockIdx.x * 4 + wave;     // b*N + q
  const float2* cq = cand + (size_t)row * 336;
  float cv[6];
  int cm[6];
#pragma unroll
  for (int i = 0; i < 6; ++i) {
    int j = lane + 64 * i;
    if (j < 336) {
      float2 p = cq[j];
      cv[i] = p.x; cm[i] = __float_as_int(p.y);
    } else {
      cv[i] = NEG_INF; cm[i] = 0x7fffffff;
    }
  }
  unsigned used = 0u;
  float bestv = NEG_INF;
  int bestm = 0x7fffffff;
#pragma unroll
  for (int i = 0; i < 6; ++i)
    if (pair_gt(cv[i], cm[i], bestv, bestm)) { bestv = cv[i]; bestm = cm[i]; }
#pragma unroll 1
  for (int sel = 0; sel <= K; ++sel) {
    float bv = bestv;
    int bm = bestm;
#pragma unroll
    for (int s = 1; s < 64; s <<= 1) {
      float ov = __shfl_xor(bv, s);
      int om = __shfl_xor(bm, s);
      if (pair_gt(ov, om, bv, bm)) { bv = ov; bm = om; }
    }
    if (sel > 0 && lane == 0)
      idxout[(size_t)row * K + (sel - 1)] = bm;
    if (bm == bestm) {   // owner lane (m unique across candidates)
#pragma unroll
      for (int i = 0; i < 6; ++i)
        if (cm[i] == bm) used |= 1u << i;
      bestv = NEG_INF; bestm = 0x7fffffff;
#pragma unroll
      for (int i = 0; i < 6; ++i)
        if (!((used >> i) & 1u) && pair_gt(cv[i], cm[i], bestv, bestm)) {
          bestv = cv[i]; bestm = cm[i];
        }
    }
  }
}

// ---------------- build [W2 ; W1-W2] from edge weight (O, 2C), fp32 ---------
__global__ void wcomb_build(const float* __restrict__ w, float* __restrict__ wc, int O, int C) {
  int i = blockIdx.x * 256 + threadIdx.x;
  if (i >= O * C) return;
  int o = i / C, c = i % C;
  float w1 = w[o * 2 * C + c];
  float w2 = w[o * 2 * C + C + c];
  wc[(size_t)o * C + c] = w2;                 // u rows
  wc[(size_t)(O + o) * C + c] = w1 - w2;      // v rows
}

// ---------------- fp32 C = A(MxK,lda) * B(NcxK)^T (UV gemms) ----------------
__global__ __launch_bounds__(256) void gemm_abt(
    const float* __restrict__ A, int lda, const float* __restrict__ Bm,
    float* __restrict__ Cm, int ldc, int M, int Nc, int K) {
  __shared__ float As[16][68];
  __shared__ float Bs[16][68];
  const int tid = threadIdx.x;
  const int tx = tid & 15, ty = tid >> 4;
  const int n0 = blockIdx.x * 64;
  const int m0 = blockIdx.y * 64;
  float acc[4][4] = {};
  const int nkt = (K + 15) / 16;
  for (int kt = 0; kt < nkt; ++kt) {
    int k0 = kt * 16;
#pragma unroll
    for (int ph = 0; ph < 4; ++ph) {
      int idx = tid + 256 * ph;
      int k = idx & 15, mr = idx >> 4;
      float v = 0.f;
      if (k0 + k < K) v = A[(size_t)(m0 + mr) * lda + k0 + k];
      As[k][mr] = v;
    }
#pragma unroll
    for (int ph = 0; ph < 4; ++ph) {
      int idx = tid + 256 * ph;
      int k = idx & 15, nr = idx >> 4;
      float v = 0.f;
      if (k0 + k < K) v = Bm[(size_t)(n0 + nr) * K + k0 + k];
      Bs[k][nr] = v;
    }
    __syncthreads();
#pragma unroll
    for (int kk = 0; kk < 16; ++kk) {
      float av[4], bv[4];
#pragma unroll
      for (int r = 0; r < 4; ++r) av[r] = As[kk][4 * ty + r];
#pragma unroll
      for (int c = 0; c < 4; ++c) bv[c] = Bs[kk][4 * tx + c];
#pragma unroll
      for (int r = 0; r < 4; ++r)
#pragma unroll
        for (int c = 0; c < 4; ++c) acc[r][c] = fmaf(av[r], bv[c], acc[r][c]);
    }
    __syncthreads();
  }
#pragma unroll
  for (int r = 0; r < 4; ++r) {
    float4 v = make_float4(acc[r][0], acc[r][1], acc[r][2], acc[r][3]);
    *(float4*)&Cm[(size_t)(m0 + 4 * ty + r) * ldc + n0 + 4 * tx] = v;
  }
}

// ---------------- MFMA bf16 GEMM: C = A(MxK) * B(NcxK)^T, fp32 out ----------
__global__ __launch_bounds__(256) void gemm_mfma_bt(
    const __hip_bfloat16* __restrict__ A, const __hip_bfloat16* __restrict__ Bm,
    float* __restrict__ Cm, int ldc, int M, int Nc, int K) {
  __shared__ __align__(16) __hip_bfloat16 Asm[128][40];
  __shared__ __align__(16) __hip_bfloat16 Bsm[128][40];
  const int tid = threadIdx.x;
  const int lane = tid & 63;
  const int wave = tid >> 6;
  const int wm = (wave >> 1) * 64;
  const int wn = (wave & 1) * 64;
  const int m0 = blockIdx.y * 128;
  const int n0 = blockIdx.x * 128;
  const int srow = tid >> 1, skq = (tid & 1) * 16;
  f32x4 acc[4][4] = {};
#pragma unroll 1
  for (int k0 = 0; k0 < K; k0 += 32) {
    short8 a0 = *(const short8*)&A[(size_t)(m0 + srow) * K + k0 + skq];
    short8 a1 = *(const short8*)&A[(size_t)(m0 + srow) * K + k0 + skq + 8];
    short8 b0 = *(const short8*)&Bm[(size_t)(n0 + srow) * K + k0 + skq];
    short8 b1 = *(const short8*)&Bm[(size_t)(n0 + srow) * K + k0 + skq + 8];
    *(short8*)&Asm[srow][skq] = a0;
    *(short8*)&Asm[srow][skq + 8] = a1;
    *(short8*)&Bsm[srow][skq] = b0;
    *(short8*)&Bsm[srow][skq + 8] = b1;
    __syncthreads();
    short8 af[4], bf_[4];
    const int fr = lane & 15, fq = (lane >> 4) * 8;
#pragma unroll
    for (int s = 0; s < 4; ++s)
      af[s] = *(const short8*)&Asm[wm + s * 16 + fr][fq];
#pragma unroll
    for (int t = 0; t < 4; ++t)
      bf_[t] = *(const short8*)&Bsm[wn + t * 16 + fr][fq];
#pragma unroll
    for (int s = 0; s < 4; ++s)
#pragma unroll
      for (int t = 0; t < 4; ++t)
        acc[s][t] = __builtin_amdgcn_mfma_f32_16x16x32_bf16(af[s], bf_[t], acc[s][t], 0, 0, 0);
    __syncthreads();
  }
  const int ccol = lane & 15, crow = (lane >> 4) * 4;
#pragma unroll
  for (int s = 0; s < 4; ++s)
#pragma unroll
    for (int t = 0; t < 4; ++t)
#pragma unroll
      for (int r = 0; r < 4; ++r) {
        int row = m0 + wm + s * 16 + crow + r;
        int col = n0 + wn + t * 16 + ccol;
        __builtin_nontemporal_store(acc[s][t][r], &Cm[(size_t)row * ldc + col]);
      }
}

// ---------------- edge conv pass1: h = v_n + u_m; stats + max/min over k ----
__global__ void edge_pass1(const float* __restrict__ uv, const int* __restrict__ idx,
                           float* __restrict__ hmax, float* __restrict__ hmin,
                           float* __restrict__ part, int N, int O, int K) {
  int b = blockIdx.y, n = blockIdx.x, o = threadIdx.x;
  size_t row = (size_t)b * N + n;
  const int twoO = 2 * O;
  float vv = uv[row * twoO + O + o];
  const int* ib = idx + row * K;
  float mx = NEG_INF, mn = POS_INF, s = 0.f, ss = 0.f;
  for (int k = 0; k < K; ++k) {
    int m = ib[k];
    float h = vv + uv[((size_t)b * N + m) * twoO + o];
    mx = fmaxf(mx, h); mn = fminf(mn, h);
    s += h; ss = fmaf(h, h, ss);
  }
  hmax[row * O + o] = mx;
  hmin[row * O + o] = mn;
  __shared__ float2 red[256];
  red[o] = make_float2(s, ss);
  __syncthreads();
  int gsz = O >> 2;
  int lane = o & (gsz - 1);
  for (int off = gsz >> 1; off > 0; off >>= 1) {
    if (lane < off) { red[o].x += red[o + off].x; red[o].y += red[o + off].y; }
    __syncthreads();
  }
  if (lane == 0) {
    int g = o / gsz;
    part[row * 8 + g * 2] = red[o].x;
    part[row * 8 + g * 2 + 1] = red[o].y;
  }
}

__global__ void stats_reduce(const float* __restrict__ part, float* __restrict__ st, int N) {
  int g = blockIdx.x, b = blockIdx.y, tid = threadIdx.x;
  float s = 0.f, ss = 0.f;
  for (int n = tid; n < N; n += 256) {
    size_t base = ((size_t)b * N + n) * 8 + g * 2;
    s += part[base]; ss += part[base + 1];
  }
  __shared__ float2 red[256];
  red[tid] = make_float2(s, ss);
  __syncthreads();
  for (int off = 128; off > 0; off >>= 1) {
    if (tid < off) { red[tid].x += red[tid + off].x; red[tid].y += red[tid + off].y; }
    __syncthreads();
  }
  if (tid == 0) { st[(b * 4 + g) * 2] = red[0].x; st[(b * 4 + g) * 2 + 1] = red[0].y; }
}

__global__ void edge_pass2(const float* __restrict__ hmax, const float* __restrict__ hmin,
                           const float* __restrict__ st,
                           const float* __restrict__ gw, const float* __restrict__ gb,
                           float* __restrict__ outbase, __hip_bfloat16* __restrict__ outbf,
                           int N, int O, int K, int coloff, int total) {
  int i = blockIdx.x * 256 + threadIdx.x;
  if (i >= total) return;
  int o = i % O;
  int n = (i / O) % N;
  int b = i / (O * N);
  int gsz = O >> 2;
  int g = o / gsz;
  float S = st[(b * 4 + g) * 2], SS = st[(b * 4 + g) * 2 + 1];
  float cnt = (float)N * (float)K * (float)gsz;
  float mean = S / cnt;
  float var = SS / cnt - mean * mean;
  float rs = rsqrtf(var + 1e-5f);
  float wf = gw[o], bf = gb[o];
  float Mv = (wf >= 0.f) ? hmax[i] : hmin[i];
  float val = lk((Mv - mean) * rs * wf + bf);
  size_t pos = ((size_t)b * N + n) * 512 + coloff + o;
  outbase[pos] = val;
  outbf[pos] = __float2bfloat16(val);
}

// ---------------- gn_seq stats: two-phase ----------------
__global__ void seq_part(const float* __restrict__ h, float4* __restrict__ pq, int N) {
  int b = blockIdx.y, chunk = blockIdx.z;
  int c = blockIdx.x * 256 + threadIdx.x;
  float mx = NEG_INF, mn = POS_INF, s = 0.f, ss = 0.f;
  int nbeg = chunk * 128;
#pragma unroll 1
  for (int n = nbeg; n < nbeg + 128; ++n) {
    float v = __builtin_nontemporal_load(&h[((size_t)b * N + n) * 1024 + c]);
    mx = fmaxf(mx, v); mn = fminf(mn, v);
    s += v; ss = fmaf(v, v, ss);
  }
  pq[((size_t)(b * 16 + chunk)) * 1024 + c] = make_float4(mx, mn, s, ss);
}

__global__ void seq_fin(const float4* __restrict__ pq, float* __restrict__ st16,
                        float* __restrict__ maxv, float* __restrict__ minv) {
  int b = blockIdx.y;
  int tid = threadIdx.x;
  int c = blockIdx.x * 256 + tid;
  float mx = NEG_INF, mn = POS_INF, s = 0.f, ss = 0.f;
#pragma unroll
  for (int ch = 0; ch < 16; ++ch) {
    float4 p = pq[((size_t)(b * 16 + ch)) * 1024 + c];
    mx = fmaxf(mx, p.x); mn = fminf(mn, p.y);
    s += p.z; ss += p.w;
  }
  maxv[b * 1024 + c] = mx;
  minv[b * 1024 + c] = mn;
  __shared__ float2 red[256];
  red[tid] = make_float2(s, ss);
  __syncthreads();
  int lane = tid & 63;
  for (int off = 32; off > 0; off >>= 1) {
    if (lane < off) { red[tid].x += red[tid + off].x; red[tid].y += red[tid + off].y; }
    __syncthreads();
  }
  if (lane == 0) {
    int g = c >> 6;
    st16[(b * 16 + g) * 2] = red[tid].x;
    st16[(b * 16 + g) * 2 + 1] = red[tid].y;
  }
}

__global__ void seq_apply(const float* __restrict__ st16, const float* __restrict__ maxv,
                          const float* __restrict__ minv, const float* __restrict__ gw,
                          const float* __restrict__ gb, float* __restrict__ g, int N) {
  int i = blockIdx.x * 256 + threadIdx.x;
  if (i >= 8 * 1024) return;
  int b = i >> 10, c = i & 1023;
  int grp = c >> 6;
  float S = st16[(b * 16 + grp) * 2], SS = st16[(b * 16 + grp) * 2 + 1];
  float cnt = (float)N * 64.f;
  float mean = S / cnt;
  float var = SS / cnt - mean * mean;
  float rs = rsqrtf(var + 1e-5f);
  float wf = gw[c], bf = gb[c];
  float Mv = (wf >= 0.f) ? maxv[i] : minv[i];
  g[i] = lk((Mv - mean) * rs * wf + bf);
}

// ---------------- fused MLP head: one block per batch ----------------
__device__ void block_fc(const float* in, int Cin, int Cout,
                         const float* __restrict__ w, const float* __restrict__ bias,
                         float* z) {
  int tid = threadIdx.x;
  for (int o = tid; o < Cout; o += 256) {
    const float* wr = w + (size_t)o * Cin;
    float acc = 0.f;
    for (int c = 0; c < Cin; c += 4) {
      float4 w4 = *(const float4*)(wr + c);
      acc = fmaf(in[c], w4.x, acc);
      acc = fmaf(in[c + 1], w4.y, acc);
      acc = fmaf(in[c + 2], w4.z, acc);
      acc = fmaf(in[c + 3], w4.w, acc);
    }
    z[o] = acc + bias[o];
  }
  __syncthreads();
}

__device__ void block_ln_leaky(const float* z, int Cn, const float* __restrict__ w,
                               const float* __restrict__ bias, float* out, float2* red) {
  int tid = threadIdx.x;
  float s = 0.f, ss = 0.f;
  for (int o = tid; o < Cn; o += 256) { float v = z[o]; s += v; ss = fmaf(v, v, ss); }
  red[tid] = make_float2(s, ss);
  __syncthreads();
  for (int off = 128; off > 0; off >>= 1) {
    if (tid < off) { red[tid].x += red[tid + off].x; red[tid].y += red[tid + off].y; }
    __syncthreads();
  }
  float mean = red[0].x / Cn;
  float var = red[0].y / Cn - mean * mean;
  float rs = rsqrtf(var + 1e-5f);
  __syncthreads();
  for (int o = tid; o < Cn; o += 256) out[o] = lk((z[o] - mean) * rs * w[o] + bias[o]);
  __syncthreads();
}

__global__ __launch_bounds__(256) void mlp_head(
    const float* __restrict__ gvec,
    const float* __restrict__ fc1w, const float* __restrict__ fc1b,
    const float* __restrict__ ln1w, const float* __restrict__ ln1b,
    const float* __restrict__ fc2w, const float* __restrict__ fc2b,
    const float* __restrict__ ln2w, const float* __restrict__ ln2b,
    const float* __restrict__ fc3w, const float* __restrict__ fc3b,
    const float* __restrict__ ln3w, const float* __restrict__ ln3b,
    const float* __restrict__ fc4w, const float* __restrict__ fc4b,
    void* __restrict__ out, const int* __restrict__ flag) {
  __shared__ float ping[1024];
  __shared__ float pong[512];
  __shared__ float2 red[256];
  const int b = blockIdx.x, tid = threadIdx.x;
  for (int i = tid; i < 1024; i += 256) ping[i] = gvec[b * 1024 + i];
  __syncthreads();
  block_fc(ping, 1024, 512, fc1w, fc1b, pong);
  block_ln_leaky(pong, 512, ln1w, ln1b, ping, red);
  block_fc(ping, 512, 256, fc2w, fc2b, pong);
  block_ln_leaky(pong, 256, ln2w, ln2b, ping, red);
  block_fc(ping, 256, 64, fc3w, fc3b, pong);
  block_ln_leaky(pong, 64, ln3w, ln3b, ping, red);
  if (tid < 2) {
    float acc = 0.f;
    for (int c = 0; c < 64; ++c) acc = fmaf(ping[c], fc4w[tid * 64 + c], acc);
    acc += fc4b[tid];
    if (*flag) ((__hip_bfloat16*)out)[b * 2 + tid] = __float2bfloat16(acc);
    else       ((float*)out)[b * 2 + tid] = acc;
  }
}

// ---------------- host-side dispatch helpers -----------------------
static void launch_sq(int C, const float* xin, int ldx, float* sqb, int BN, hipStream_t s) {
  dim3 g((BN + 255) / 256);
  if (C == 3)       sq_kernel<3><<<g, 256, 0, s>>>(xin, ldx, sqb, BN);
  else if (C == 64) sq_kernel<64><<<g, 256, 0, s>>>(xin, ldx, sqb, BN);
  else              sq_kernel<128><<<g, 256, 0, s>>>(xin, ldx, sqb, BN);
}

extern "C" void kernel_launch(void* const* d_in, const int* in_sizes, int n_in,
                              void* d_out, int out_size, void* d_ws, size_t ws_size,
                              hipStream_t stream) {
  (void)out_size; (void)ws_size;
  const int B = 8, N = 2048, KNN = 20;
  const int BN = B * N;

  float* base = (float*)d_ws;
  size_t off = 0;
  auto alloc = [&](size_t nf) { float* p = base + off; off += nf; return p; };

  int*   FLAG  = (int*)alloc(16);
  float* XF    = alloc((size_t)BN * 3);
  float* XFP   = alloc((size_t)BN * 16);
  float* HCAT  = alloc((size_t)BN * 512);
  float* DISTB = alloc((size_t)BN * 2048);   // UV|HMAX|HMIN | CAND | H1024
  float* UV    = DISTB;                       // BN*512
  float* HMAX  = DISTB + (size_t)BN * 512;    // BN*256
  float* HMIN  = DISTB + (size_t)BN * 768;    // BN*256
  float* H1024 = DISTB + (size_t)BN * 1024;   // BN*1024 (after layer loop)
  float2* CAND = (float2*)(DISTB + (size_t)BN * 1024);  // BN*336 float2 (44MB) during layers
  float* SQB   = alloc(BN);
  float* WCOMB = alloc((size_t)512 * 128);
  float* PART  = alloc((size_t)BN * 8);
  float* ST4   = alloc(64);
  float* ST16  = alloc(512);
  float* PQST  = alloc((size_t)8 * 16 * 1024 * 4);
  float* MAXV  = alloc(8 * 1024);
  float* MINV  = alloc(8 * 1024);
  float* GVEC  = alloc(8 * 1024);
  int*   IDX = (int*)alloc((size_t)BN * KNN);
  __hip_bfloat16* HCATBF = (__hip_bfloat16*)alloc((size_t)BN * 256);  // BN*512 bf16
  __hip_bfloat16* WMBF   = (__hip_bfloat16*)alloc(262144);            // 1024*512 bf16

  // converted fp32 weights
  ConvTable ct;
  float* conv_dst[30];
  for (int i = 0; i < 30; ++i) {
    int n = in_sizes[i];
    conv_dst[i] = alloc((size_t)((n + 15) & ~15));
    ct.src[i] = d_in[i];
    ct.dst[i] = conv_dst[i];
    ct.n[i] = n;
  }
  ct.dst[0] = XF; ct.n[0] = BN * 3;

  const float* W_[4]  = {conv_dst[1], conv_dst[4], conv_dst[7], conv_dst[10]};
  const float* GW_[4] = {conv_dst[2], conv_dst[5], conv_dst[8], conv_dst[11]};
  const float* GB_[4] = {conv_dst[3], conv_dst[6], conv_dst[9], conv_dst[12]};
  const float* WM = conv_dst[13];
  const float* GMW = conv_dst[14], *GMB = conv_dst[15];
  const float* FC1W = conv_dst[16], *FC1B = conv_dst[17], *LN1W = conv_dst[18], *LN1B = conv_dst[19];
  const float* FC2W = conv_dst[20], *FC2B = conv_dst[21], *LN2W = conv_dst[22], *LN2B = conv_dst[23];
  const float* FC3W = conv_dst[24], *FC3B = conv_dst[25], *LN3W = conv_dst[26], *LN3B = conv_dst[27];
  const float* FC4W = conv_dst[28], *FC4B = conv_dst[29];

  detect_dtype<<<dim3(1), 64, 0, stream>>>((const unsigned short*)d_in[0], FLAG);
  conv_all<<<dim3(256, 30), 256, 0, stream>>>(ct, FLAG);
  convf2b<<<dim3(2048), 256, 0, stream>>>(WM, WMBF, 1024 * 512);
  xpad<<<dim3((BN * 16 + 255) / 256), 256, 0, stream>>>(XF, XFP, BN * 16);

  const int Cs[4]     = {3, 64, 64, 128};
  const int Os[4]     = {64, 64, 128, 256};
  const int incol[4]  = {0, 0, 64, 128};
  const int outcol[4] = {0, 64, 128, 256};

  for (int l = 0; l < 4; ++l) {
    const int C = Cs[l], O = Os[l], twoO = 2 * O;
    const float* xin = (l == 0) ? XF : (HCAT + incol[l]);
    const int ldx = (l == 0) ? 3 : 512;

    launch_sq(C, xin, ldx, SQB, BN, stream);
    if (l == 0)
      dist_sel<<<dim3(16, 16, 8), 256, 0, stream>>>(XFP, 16, SQB, CAND, N, 16);
    else
      dist_sel<<<dim3(16, 16, 8), 256, 0, stream>>>(xin, 512, SQB, CAND, N, C);
    knn_sel2<<<dim3(BN / 4), 256, 0, stream>>>(CAND, IDX, KNN);
    wcomb_build<<<dim3((O * C + 255) / 256), 256, 0, stream>>>(W_[l], WCOMB, O, C);
    gemm_abt<<<dim3(twoO / 64, BN / 64), 256, 0, stream>>>(xin, ldx, WCOMB, UV, twoO, BN, twoO, C);
    edge_pass1<<<dim3(N, B), O, 0, stream>>>(UV, IDX, HMAX, HMIN, PART, N, O, KNN);
    stats_reduce<<<dim3(4, B), 256, 0, stream>>>(PART, ST4, N);
    int tot = BN * O;
    edge_pass2<<<dim3((tot + 255) / 256), 256, 0, stream>>>(HMAX, HMIN, ST4, GW_[l], GB_[l],
                                                            HCAT, HCATBF, N, O, KNN, outcol[l], tot);
  }

  gemm_mfma_bt<<<dim3(1024 / 128, BN / 128), 256, 0, stream>>>(HCATBF, WMBF, H1024, 1024, BN, 1024, 512);
  seq_part<<<dim3(4, 8, 16), 256, 0, stream>>>(H1024, (float4*)PQST, N);
  seq_fin<<<dim3(4, 8), 256, 0, stream>>>((const float4*)PQST, ST16, MAXV, MINV);
  seq_apply<<<dim3(32), 256, 0, stream>>>(ST16, MAXV, MINV, GMW, GMB, GVEC, N);

  mlp_head<<<dim3(8), 256, 0, stream>>>(GVEC, FC1W, FC1B, LN1W, LN1B,
                                        FC2W, FC2B, LN2W, LN2B,
                                        FC3W, FC3B, LN3W, LN3B,
                                        FC4W, FC4B, d_out, FLAG);
}

// Round 16
// 1026.933 us; speedup vs baseline: 8.8820x; 2.1510x over previous
//
#include <hip/hip_runtime.h>
#include <hip/hip_bf16.h>

// DGCNN forward on MI355X. B=8, N=2048, K=20.
// Round 16: REVERT to round-13 structure (1154us, passed) -- round-15 proved
// in-kernel per-slice top-21 extraction costs 4x the DIST round-trip it saves
// (405us/dispatch, C-invariant, VALU-bound). On top of r13:
//  (1) knn_select first-pass loads are PLAIN (not NT): DIST 134MB < L3 256MB,
//      NT loads force HBM reads of possibly L3-resident lines.
//  (2) edge_pass1: K=20 compile-time, prefetch 20 indices then 20 independent
//      gathers (was a serialized dependent-load chain). Chains preserved.

#define NEG_INF (-3.402823466e38f)
#define POS_INF (3.402823466e38f)

typedef __attribute__((ext_vector_type(8))) short short8;
typedef __attribute__((ext_vector_type(4))) float f32x4;

__device__ __forceinline__ float lk(float x) { return x > 0.f ? x : 0.2f * x; }

__device__ __forceinline__ bool pair_gt(float va, int ma, float vb, int mb) {
  return va > vb || (va == vb && ma < mb);
}

// ---------------- dtype probe: 1 = bf16, 0 = fp32 ----------------
__global__ void detect_dtype(const unsigned short* __restrict__ x16, int* __restrict__ flag) {
  if (threadIdx.x == 0 && blockIdx.x == 0) {
    int sane = 0;
    for (int i = 0; i < 64; ++i) {
      unsigned short u = x16[2 * i];
      int e = (u >> 7) & 0xff;
      if (e == 0 || (e >= 90 && e <= 140)) ++sane;
    }
    *flag = (sane >= 32) ? 1 : 0;
  }
}

// ---------------- batched convert-to-fp32 of all inputs ----------------
struct ConvTable {
  const void* src[30];
  float* dst[30];
  int n[30];
};

__global__ void conv_all(ConvTable t, const int* __restrict__ flag) {
  int e = blockIdx.y;
  int n = t.n[e];
  bool isbf = (*flag != 0);
  for (int i = blockIdx.x * 256 + threadIdx.x; i < n; i += gridDim.x * 256) {
    float v;
    if (isbf) v = __bfloat162float(((const __hip_bfloat16*)t.src[e])[i]);
    else      v = ((const float*)t.src[e])[i];
    t.dst[e][i] = v;
  }
}

__global__ void convf2b(const float* __restrict__ in, __hip_bfloat16* __restrict__ out, int n) {
  int i = blockIdx.x * 256 + threadIdx.x;
  if (i < n) out[i] = __float2bfloat16(in[i]);
}

// ---------------- squared norms: SINGLE fmaf chain ascending c --------------
template <int C>
__global__ void sq_kernel(const float* __restrict__ xin, int ldx, float* __restrict__ sqb, int total) {
  int i = blockIdx.x * 256 + threadIdx.x;
  if (i >= total) return;
  const float* p = xin + (size_t)i * ldx;
  float s = 0.f;
  if (C == 3) {
    s = fmaf(p[0], p[0], s); s = fmaf(p[1], p[1], s); s = fmaf(p[2], p[2], s);
  } else {
#pragma unroll
    for (int c = 0; c < C; c += 4) {
      float4 xv = *(const float4*)(p + c);
      s = fmaf(xv.x, xv.x, s);
      s = fmaf(xv.y, xv.y, s);
      s = fmaf(xv.z, xv.z, s);
      s = fmaf(xv.w, xv.w, s);
    }
  }
  sqb[i] = s;
}

// ---------------- distance GEMM (C==3, layer 1): exact fp32 ----------------
__global__ __launch_bounds__(256) void dist_gemm(
    const float* __restrict__ xin, int ldx, const float* __restrict__ sqb,
    float* __restrict__ dist, int N, int K) {
  __shared__ float As[16][68];
  __shared__ float Bs[16][68];
  const int tid = threadIdx.x;
  const int tx = tid & 15, ty = tid >> 4;
  const int mc0 = blockIdx.x * 64;
  const int qr0 = blockIdx.y * 64;
  const int b = blockIdx.z;
  float acc[4][4] = {};
  const int nkt = (K + 15) / 16;
  for (int kt = 0; kt < nkt; ++kt) {
    int k0 = kt * 16;
#pragma unroll
    for (int ph = 0; ph < 4; ++ph) {
      int idx = tid + 256 * ph;
      int k = idx & 15, r = idx >> 4;
      float v = 0.f;
      if (k0 + k < K) v = xin[(size_t)(b * N + qr0 + r) * ldx + k0 + k];
      As[k][r] = v;
    }
#pragma unroll
    for (int ph = 0; ph < 4; ++ph) {
      int idx = tid + 256 * ph;
      int k = idx & 15, r = idx >> 4;
      float v = 0.f;
      if (k0 + k < K) v = xin[(size_t)(b * N + mc0 + r) * ldx + k0 + k];
      Bs[k][r] = v;
    }
    __syncthreads();
#pragma unroll
    for (int kk = 0; kk < 16; ++kk) {
      float av[4], bv[4];
#pragma unroll
      for (int r = 0; r < 4; ++r) av[r] = As[kk][4 * ty + r];
#pragma unroll
      for (int c = 0; c < 4; ++c) bv[c] = Bs[kk][4 * tx + c];
#pragma unroll
      for (int r = 0; r < 4; ++r)
#pragma unroll
        for (int c = 0; c < 4; ++c) acc[r][c] = fmaf(av[r], bv[c], acc[r][c]);
    }
    __syncthreads();
  }
  float sqq[4], sqm[4];
#pragma unroll
  for (int r = 0; r < 4; ++r) sqq[r] = sqb[b * N + qr0 + 4 * ty + r];
#pragma unroll
  for (int c = 0; c < 4; ++c) sqm[c] = sqb[b * N + mc0 + 4 * tx + c];
#pragma unroll
  for (int r = 0; r < 4; ++r) {
    f32x4 o;
#pragma unroll
    for (int c = 0; c < 4; ++c) {
      float t = sqq[r] - 2.f * acc[r][c];
      t = t + sqm[c];
      o[c] = -t;
    }
    __builtin_nontemporal_store(o, (f32x4*)&dist[((size_t)(b * N + qr0 + 4 * ty + r)) * 2048 + mc0 + 4 * tx]);
  }
}

// ---------------- distance GEMM (C in {64,128}, ldx=512): 128x128, 8x8 -----
// EXACT fp32; same ascending-k fmaf chain per element as sq_kernel =>
// self-distance exactly 0. Columns split as [4tx] and [64+4tx]: dense stores.
__global__ __launch_bounds__(256, 4) void dist_gemm128(
    const float* __restrict__ xin, const float* __restrict__ sqb,
    float* __restrict__ dist, int N, int K) {
  __shared__ float As[16][132];
  __shared__ float Bs[16][132];
  const int tid = threadIdx.x;
  const int tx = tid & 15, ty = tid >> 4;
  const int mc0 = blockIdx.x * 128;
  const int qr0 = blockIdx.y * 128;
  const int b = blockIdx.z;
  float acc[8][8] = {};
  const int row = tid >> 1, kq = (tid & 1) * 8;
#pragma unroll 1
  for (int k0 = 0; k0 < K; k0 += 16) {
    float4 a0 = *(const float4*)&xin[(size_t)(b * N + qr0 + row) * 512 + k0 + kq];
    float4 a1 = *(const float4*)&xin[(size_t)(b * N + qr0 + row) * 512 + k0 + kq + 4];
    float4 b0 = *(const float4*)&xin[(size_t)(b * N + mc0 + row) * 512 + k0 + kq];
    float4 b1 = *(const float4*)&xin[(size_t)(b * N + mc0 + row) * 512 + k0 + kq + 4];
#pragma unroll
    for (int j = 0; j < 4; ++j) {
      As[kq + j][row] = (&a0.x)[j];
      As[kq + 4 + j][row] = (&a1.x)[j];
      Bs[kq + j][row] = (&b0.x)[j];
      Bs[kq + 4 + j][row] = (&b1.x)[j];
    }
    __syncthreads();
#pragma unroll
    for (int kk = 0; kk < 16; ++kk) {
      float av[8], bv[8];
      *(float4*)&av[0] = *(const float4*)&As[kk][8 * ty];
      *(float4*)&av[4] = *(const float4*)&As[kk][8 * ty + 4];
      *(float4*)&bv[0] = *(const float4*)&Bs[kk][4 * tx];
      *(float4*)&bv[4] = *(const float4*)&Bs[kk][64 + 4 * tx];
#pragma unroll
      for (int r = 0; r < 8; ++r)
#pragma unroll
        for (int c = 0; c < 8; ++c) acc[r][c] = fmaf(av[r], bv[c], acc[r][c]);
    }
    __syncthreads();
  }
  float sqq[8], sqm[8];
#pragma unroll
  for (int r = 0; r < 8; ++r) sqq[r] = sqb[b * N + qr0 + 8 * ty + r];
#pragma unroll
  for (int c = 0; c < 4; ++c) {
    sqm[c]     = sqb[b * N + mc0 + 4 * tx + c];
    sqm[c + 4] = sqb[b * N + mc0 + 64 + 4 * tx + c];
  }
#pragma unroll
  for (int r = 0; r < 8; ++r) {
    f32x4 o0, o1;
#pragma unroll
    for (int c = 0; c < 4; ++c) {
      float t = sqq[r] - 2.f * acc[r][c];
      t = t + sqm[c];
      o0[c] = -t;
      float t2 = sqq[r] - 2.f * acc[r][c + 4];
      t2 = t2 + sqm[c + 4];
      o1[c] = -t2;
    }
    size_t rowbase = ((size_t)(b * N + qr0 + 8 * ty + r)) * 2048 + mc0;
    __builtin_nontemporal_store(o0, (f32x4*)&dist[rowbase + 4 * tx]);
    __builtin_nontemporal_store(o1, (f32x4*)&dist[rowbase + 64 + 4 * tx]);
  }
}

// ---------------- knn selection: one wave per query, register top-4 queue ---
// First-pass loads are PLAIN (not NT): DIST may be L3-resident (134MB<256MB).
__global__ __launch_bounds__(256) void knn_select(
    const float* __restrict__ dist, int* __restrict__ idxout, int K) {
  const int lane = threadIdx.x & 63;
  const int wave = threadIdx.x >> 6;
  const int row = blockIdx.x * 4 + wave;     // b*N + q
  const float* dr = dist + (size_t)row * 2048;

  float f0 = NEG_INF, f1 = NEG_INF, f2 = NEG_INF, f3 = NEG_INF;
  int   m0 = 0x7fffffff, m1 = 0x7fffffff, m2 = 0x7fffffff, m3 = 0x7fffffff;

#pragma unroll
  for (int i = 0; i < 8; ++i) {
    float4 vv = *(const float4*)(dr + i * 256 + lane * 4);
#pragma unroll
    for (int c = 0; c < 4; ++c) {
      float v = (&vv.x)[c];
      int m = i * 256 + lane * 4 + c;
      if (pair_gt(v, m, f3, m3)) {
        bool b2 = pair_gt(v, m, f2, m2);
        bool b1 = pair_gt(v, m, f1, m1);
        bool b0 = pair_gt(v, m, f0, m0);
        f3 = b2 ? f2 : v;              m3 = b2 ? m2 : m;
        f2 = b1 ? f1 : (b2 ? v : f2);  m2 = b1 ? m1 : (b2 ? m : m2);
        f1 = b0 ? f0 : (b1 ? v : f1);  m1 = b0 ? m0 : (b1 ? m : m1);
        f0 = b0 ? v : f0;              m0 = b0 ? m : m0;
      }
    }
  }
  int rem = 4;

#pragma unroll 1
  for (int sel = 0; sel <= K; ++sel) {
    float bv = f0;
    int bm = m0;
#pragma unroll
    for (int s = 1; s < 64; s <<= 1) {
      float ov = __shfl_xor(bv, s);
      int om = __shfl_xor(bm, s);
      if (pair_gt(ov, om, bv, bm)) { bv = ov; bm = om; }
    }
    if (sel > 0 && lane == 0)
      idxout[(size_t)row * K + (sel - 1)] = bm;
    if (((bm >> 2) & 63) == lane) {
      f0 = f1; m0 = m1; f1 = f2; m1 = m2; f2 = f3; m2 = m3;
      f3 = NEG_INF; m3 = 0x7fffffff;
      if (--rem == 0) {
        f0 = f1 = f2 = f3 = NEG_INF;
        m0 = m1 = m2 = m3 = 0x7fffffff;
#pragma unroll 1
        for (int i = 0; i < 8; ++i) {
          float4 vv = *(const float4*)(dr + i * 256 + lane * 4);
#pragma unroll
          for (int c = 0; c < 4; ++c) {
            float v = (&vv.x)[c];
            int m = i * 256 + lane * 4 + c;
            if (pair_gt(bv, bm, v, m) && pair_gt(v, m, f3, m3)) {
              bool b2 = pair_gt(v, m, f2, m2);
              bool b1 = pair_gt(v, m, f1, m1);
              bool b0 = pair_gt(v, m, f0, m0);
              f3 = b2 ? f2 : v;              m3 = b2 ? m2 : m;
              f2 = b1 ? f1 : (b2 ? v : f2);  m2 = b1 ? m1 : (b2 ? m : m2);
              f1 = b0 ? f0 : (b1 ? v : f1);  m1 = b0 ? m0 : (b1 ? m : m1);
              f0 = b0 ? v : f0;              m0 = b0 ? m : m0;
            }
          }
        }
        rem = 4;
      }
    }
  }
}

// ---------------- build [W2 ; W1-W2] from edge weight (O, 2C), fp32 ---------
__global__ void wcomb_build(const float* __restrict__ w, float* __restrict__ wc, int O, int C) {
  int i = blockIdx.x * 256 + threadIdx.x;
  if (i >= O * C) return;
  int o = i / C, c = i % C;
  float w1 = w[o * 2 * C + c];
  float w2 = w[o * 2 * C + C + c];
  wc[(size_t)o * C + c] = w2;                 // u rows
  wc[(size_t)(O + o) * C + c] = w1 - w2;      // v rows
}

// ---------------- fp32 C = A(MxK,lda) * B(NcxK)^T (UV gemms) ----------------
__global__ __launch_bounds__(256) void gemm_abt(
    const float* __restrict__ A, int lda, const float* __restrict__ Bm,
    float* __restrict__ Cm, int ldc, int M, int Nc, int K) {
  __shared__ float As[16][68];
  __shared__ float Bs[16][68];
  const int tid = threadIdx.x;
  const int tx = tid & 15, ty = tid >> 4;
  const int n0 = blockIdx.x * 64;
  const int m0 = blockIdx.y * 64;
  float acc[4][4] = {};
  const int nkt = (K + 15) / 16;
  for (int kt = 0; kt < nkt; ++kt) {
    int k0 = kt * 16;
#pragma unroll
    for (int ph = 0; ph < 4; ++ph) {
      int idx = tid + 256 * ph;
      int k = idx & 15, mr = idx >> 4;
      float v = 0.f;
      if (k0 + k < K) v = A[(size_t)(m0 + mr) * lda + k0 + k];
      As[k][mr] = v;
    }
#pragma unroll
    for (int ph = 0; ph < 4; ++ph) {
      int idx = tid + 256 * ph;
      int k = idx & 15, nr = idx >> 4;
      float v = 0.f;
      if (k0 + k < K) v = Bm[(size_t)(n0 + nr) * K + k0 + k];
      Bs[k][nr] = v;
    }
    __syncthreads();
#pragma unroll
    for (int kk = 0; kk < 16; ++kk) {
      float av[4], bv[4];
#pragma unroll
      for (int r = 0; r < 4; ++r) av[r] = As[kk][4 * ty + r];
#pragma unroll
      for (int c = 0; c < 4; ++c) bv[c] = Bs[kk][4 * tx + c];
#pragma unroll
      for (int r = 0; r < 4; ++r)
#pragma unroll
        for (int c = 0; c < 4; ++c) acc[r][c] = fmaf(av[r], bv[c], acc[r][c]);
    }
    __syncthreads();
  }
#pragma unroll
  for (int r = 0; r < 4; ++r) {
    float4 v = make_float4(acc[r][0], acc[r][1], acc[r][2], acc[r][3]);
    *(float4*)&Cm[(size_t)(m0 + 4 * ty + r) * ldc + n0 + 4 * tx] = v;
  }
}

// ---------------- MFMA bf16 GEMM: C = A(MxK) * B(NcxK)^T, fp32 out ----------
__global__ __launch_bounds__(256) void gemm_mfma_bt(
    const __hip_bfloat16* __restrict__ A, const __hip_bfloat16* __restrict__ Bm,
    float* __restrict__ Cm, int ldc, int M, int Nc, int K) {
  __shared__ __align__(16) __hip_bfloat16 Asm[128][40];
  __shared__ __align__(16) __hip_bfloat16 Bsm[128][40];
  const int tid = threadIdx.x;
  const int lane = tid & 63;
  const int wave = tid >> 6;
  const int wm = (wave >> 1) * 64;
  const int wn = (wave & 1) * 64;
  const int m0 = blockIdx.y * 128;
  const int n0 = blockIdx.x * 128;
  const int srow = tid >> 1, skq = (tid & 1) * 16;
  f32x4 acc[4][4] = {};
#pragma unroll 1
  for (int k0 = 0; k0 < K; k0 += 32) {
    short8 a0 = *(const short8*)&A[(size_t)(m0 + srow) * K + k0 + skq];
    short8 a1 = *(const short8*)&A[(size_t)(m0 + srow) * K + k0 + skq + 8];
    short8 b0 = *(const short8*)&Bm[(size_t)(n0 + srow) * K + k0 + skq];
    short8 b1 = *(const short8*)&Bm[(size_t)(n0 + srow) * K + k0 + skq + 8];
    *(short8*)&Asm[srow][skq] = a0;
    *(short8*)&Asm[srow][skq + 8] = a1;
    *(short8*)&Bsm[srow][skq] = b0;
    *(short8*)&Bsm[srow][skq + 8] = b1;
    __syncthreads();
    short8 af[4], bf_[4];
    const int fr = lane & 15, fq = (lane >> 4) * 8;
#pragma unroll
    for (int s = 0; s < 4; ++s)
      af[s] = *(const short8*)&Asm[wm + s * 16 + fr][fq];
#pragma unroll
    for (int t = 0; t < 4; ++t)
      bf_[t] = *(const short8*)&Bsm[wn + t * 16 + fr][fq];
#pragma unroll
    for (int s = 0; s < 4; ++s)
#pragma unroll
      for (int t = 0; t < 4; ++t)
        acc[s][t] = __builtin_amdgcn_mfma_f32_16x16x32_bf16(af[s], bf_[t], acc[s][t], 0, 0, 0);
    __syncthreads();
  }
  const int ccol = lane & 15, crow = (lane >> 4) * 4;
#pragma unroll
  for (int s = 0; s < 4; ++s)
#pragma unroll
    for (int t = 0; t < 4; ++t)
#pragma unroll
      for (int r = 0; r < 4; ++r) {
        int row = m0 + wm + s * 16 + crow + r;
        int col = n0 + wn + t * 16 + ccol;
        __builtin_nontemporal_store(acc[s][t][r], &Cm[(size_t)row * ldc + col]);
      }
}

// ---------------- edge conv pass1: h = v_n + u_m; stats + max/min over k ----
// K=20 hardcoded; all 20 indices prefetched then 20 independent gathers
// (was a serialized idx-load -> gather dependent chain). Sum chains preserved.
__global__ void edge_pass1(const float* __restrict__ uv, const int* __restrict__ idx,
                           float* __restrict__ hmax, float* __restrict__ hmin,
                           float* __restrict__ part, int N, int O) {
  int b = blockIdx.y, n = blockIdx.x, o = threadIdx.x;
  size_t row = (size_t)b * N + n;
  const int twoO = 2 * O;
  float vv = uv[row * twoO + O + o];
  const int* ib = idx + row * 20;
  int mi[20];
#pragma unroll
  for (int k = 0; k < 20; ++k) mi[k] = ib[k];
  float hv[20];
#pragma unroll
  for (int k = 0; k < 20; ++k)
    hv[k] = vv + uv[((size_t)b * N + mi[k]) * twoO + o];
  float mx = NEG_INF, mn = POS_INF, s = 0.f, ss = 0.f;
#pragma unroll
  for (int k = 0; k < 20; ++k) {
    mx = fmaxf(mx, hv[k]); mn = fminf(mn, hv[k]);
    s += hv[k]; ss = fmaf(hv[k], hv[k], ss);
  }
  hmax[row * O + o] = mx;
  hmin[row * O + o] = mn;
  __shared__ float2 red[256];
  red[o] = make_float2(s, ss);
  __syncthreads();
  int gsz = O >> 2;
  int lane = o & (gsz - 1);
  for (int off = gsz >> 1; off > 0; off >>= 1) {
    if (lane < off) { red[o].x += red[o + off].x; red[o].y += red[o + off].y; }
    __syncthreads();
  }
  if (lane == 0) {
    int g = o / gsz;
    part[row * 8 + g * 2] = red[o].x;
    part[row * 8 + g * 2 + 1] = red[o].y;
  }
}

__global__ void stats_reduce(const float* __restrict__ part, float* __restrict__ st, int N) {
  int g = blockIdx.x, b = blockIdx.y, tid = threadIdx.x;
  float s = 0.f, ss = 0.f;
  for (int n = tid; n < N; n += 256) {
    size_t base = ((size_t)b * N + n) * 8 + g * 2;
    s += part[base]; ss += part[base + 1];
  }
  __shared__ float2 red[256];
  red[tid] = make_float2(s, ss);
  __syncthreads();
  for (int off = 128; off > 0; off >>= 1) {
    if (tid < off) { red[tid].x += red[tid + off].x; red[tid].y += red[tid + off].y; }
    __syncthreads();
  }
  if (tid == 0) { st[(b * 4 + g) * 2] = red[0].x; st[(b * 4 + g) * 2 + 1] = red[0].y; }
}

__global__ void edge_pass2(const float* __restrict__ hmax, const float* __restrict__ hmin,
                           const float* __restrict__ st,
                           const float* __restrict__ gw, const float* __restrict__ gb,
                           float* __restrict__ outbase, __hip_bfloat16* __restrict__ outbf,
                           int N, int O, int K, int coloff, int total) {
  int i = blockIdx.x * 256 + threadIdx.x;
  if (i >= total) return;
  int o = i % O;
  int n = (i / O) % N;
  int b = i / (O * N);
  int gsz = O >> 2;
  int g = o / gsz;
  float S = st[(b * 4 + g) * 2], SS = st[(b * 4 + g) * 2 + 1];
  float cnt = (float)N * (float)K * (float)gsz;
  float mean = S / cnt;
  float var = SS / cnt - mean * mean;
  float rs = rsqrtf(var + 1e-5f);
  float wf = gw[o], bf = gb[o];
  float Mv = (wf >= 0.f) ? hmax[i] : hmin[i];
  float val = lk((Mv - mean) * rs * wf + bf);
  size_t pos = ((size_t)b * N + n) * 512 + coloff + o;
  outbase[pos] = val;
  outbf[pos] = __float2bfloat16(val);
}

// ---------------- gn_seq stats: two-phase ----------------
__global__ void seq_part(const float* __restrict__ h, float4* __restrict__ pq, int N) {
  int b = blockIdx.y, chunk = blockIdx.z;
  int c = blockIdx.x * 256 + threadIdx.x;
  float mx = NEG_INF, mn = POS_INF, s = 0.f, ss = 0.f;
  int nbeg = chunk * 128;
#pragma unroll 1
  for (int n = nbeg; n < nbeg + 128; ++n) {
    float v = __builtin_nontemporal_load(&h[((size_t)b * N + n) * 1024 + c]);
    mx = fmaxf(mx, v); mn = fminf(mn, v);
    s += v; ss = fmaf(v, v, ss);
  }
  pq[((size_t)(b * 16 + chunk)) * 1024 + c] = make_float4(mx, mn, s, ss);
}

__global__ void seq_fin(const float4* __restrict__ pq, float* __restrict__ st16,
                        float* __restrict__ maxv, float* __restrict__ minv) {
  int b = blockIdx.y;
  int tid = threadIdx.x;
  int c = blockIdx.x * 256 + tid;
  float mx = NEG_INF, mn = POS_INF, s = 0.f, ss = 0.f;
#pragma unroll
  for (int ch = 0; ch < 16; ++ch) {
    float4 p = pq[((size_t)(b * 16 + ch)) * 1024 + c];
    mx = fmaxf(mx, p.x); mn = fminf(mn, p.y);
    s += p.z; ss += p.w;
  }
  maxv[b * 1024 + c] = mx;
  minv[b * 1024 + c] = mn;
  __shared__ float2 red[256];
  red[tid] = make_float2(s, ss);
  __syncthreads();
  int lane = tid & 63;
  for (int off = 32; off > 0; off >>= 1) {
    if (lane < off) { red[tid].x += red[tid + off].x; red[tid].y += red[tid + off].y; }
    __syncthreads();
  }
  if (lane == 0) {
    int g = c >> 6;
    st16[(b * 16 + g) * 2] = red[tid].x;
    st16[(b * 16 + g) * 2 + 1] = red[tid].y;
  }
}

__global__ void seq_apply(const float* __restrict__ st16, const float* __restrict__ maxv,
                          const float* __restrict__ minv, const float* __restrict__ gw,
                          const float* __restrict__ gb, float* __restrict__ g, int N) {
  int i = blockIdx.x * 256 + threadIdx.x;
  if (i >= 8 * 1024) return;
  int b = i >> 10, c = i & 1023;
  int grp = c >> 6;
  float S = st16[(b * 16 + grp) * 2], SS = st16[(b * 16 + grp) * 2 + 1];
  float cnt = (float)N * 64.f;
  float mean = S / cnt;
  float var = SS / cnt - mean * mean;
  float rs = rsqrtf(var + 1e-5f);
  float wf = gw[c], bf = gb[c];
  float Mv = (wf >= 0.f) ? maxv[i] : minv[i];
  g[i] = lk((Mv - mean) * rs * wf + bf);
}

// ---------------- fused MLP head: one block per batch ----------------
__device__ void block_fc(const float* in, int Cin, int Cout,
                         const float* __restrict__ w, const float* __restrict__ bias,
                         float* z) {
  int tid = threadIdx.x;
  for (int o = tid; o < Cout; o += 256) {
    const float* wr = w + (size_t)o * Cin;
    float acc = 0.f;
    for (int c = 0; c < Cin; c += 4) {
      float4 w4 = *(const float4*)(wr + c);
      acc = fmaf(in[c], w4.x, acc);
      acc = fmaf(in[c + 1], w4.y, acc);
      acc = fmaf(in[c + 2], w4.z, acc);
      acc = fmaf(in[c + 3], w4.w, acc);
    }
    z[o] = acc + bias[o];
  }
  __syncthreads();
}

__device__ void block_ln_leaky(const float* z, int Cn, const float* __restrict__ w,
                               const float* __restrict__ bias, float* out, float2* red) {
  int tid = threadIdx.x;
  float s = 0.f, ss = 0.f;
  for (int o = tid; o < Cn; o += 256) { float v = z[o]; s += v; ss = fmaf(v, v, ss); }
  red[tid] = make_float2(s, ss);
  __syncthreads();
  for (int off = 128; off > 0; off >>= 1) {
    if (tid < off) { red[tid].x += red[tid + off].x; red[tid].y += red[tid + off].y; }
    __syncthreads();
  }
  float mean = red[0].x / Cn;
  float var = red[0].y / Cn - mean * mean;
  float rs = rsqrtf(var + 1e-5f);
  __syncthreads();
  for (int o = tid; o < Cn; o += 256) out[o] = lk((z[o] - mean) * rs * w[o] + bias[o]);
  __syncthreads();
}

__global__ __launch_bounds__(256) void mlp_head(
    const float* __restrict__ gvec,
    const float* __restrict__ fc1w, const float* __restrict__ fc1b,
    const float* __restrict__ ln1w, const float* __restrict__ ln1b,
    const float* __restrict__ fc2w, const float* __restrict__ fc2b,
    const float* __restrict__ ln2w, const float* __restrict__ ln2b,
    const float* __restrict__ fc3w, const float* __restrict__ fc3b,
    const float* __restrict__ ln3w, const float* __restrict__ ln3b,
    const float* __restrict__ fc4w, const float* __restrict__ fc4b,
    void* __restrict__ out, const int* __restrict__ flag) {
  __shared__ float ping[1024];
  __shared__ float pong[512];
  __shared__ float2 red[256];
  const int b = blockIdx.x, tid = threadIdx.x;
  for (int i = tid; i < 1024; i += 256) ping[i] = gvec[b * 1024 + i];
  __syncthreads();
  block_fc(ping, 1024, 512, fc1w, fc1b, pong);
  block_ln_leaky(pong, 512, ln1w, ln1b, ping, red);
  block_fc(ping, 512, 256, fc2w, fc2b, pong);
  block_ln_leaky(pong, 256, ln2w, ln2b, ping, red);
  block_fc(ping, 256, 64, fc3w, fc3b, pong);
  block_ln_leaky(pong, 64, ln3w, ln3b, ping, red);
  if (tid < 2) {
    float acc = 0.f;
    for (int c = 0; c < 64; ++c) acc = fmaf(ping[c], fc4w[tid * 64 + c], acc);
    acc += fc4b[tid];
    if (*flag) ((__hip_bfloat16*)out)[b * 2 + tid] = __float2bfloat16(acc);
    else       ((float*)out)[b * 2 + tid] = acc;
  }
}

// ---------------- host-side dispatch helpers -----------------------
static void launch_sq(int C, const float* xin, int ldx, float* sqb, int BN, hipStream_t s) {
  dim3 g((BN + 255) / 256);
  if (C == 3)       sq_kernel<3><<<g, 256, 0, s>>>(xin, ldx, sqb, BN);
  else if (C == 64) sq_kernel<64><<<g, 256, 0, s>>>(xin, ldx, sqb, BN);
  else              sq_kernel<128><<<g, 256, 0, s>>>(xin, ldx, sqb, BN);
}

extern "C" void kernel_launch(void* const* d_in, const int* in_sizes, int n_in,
                              void* d_out, int out_size, void* d_ws, size_t ws_size,
                              hipStream_t stream) {
  (void)out_size; (void)ws_size;
  const int B = 8, N = 2048, KNN = 20;
  const int BN = B * N;

  float* base = (float*)d_ws;
  size_t off = 0;
  auto alloc = [&](size_t nf) { float* p = base + off; off += nf; return p; };

  int*   FLAG  = (int*)alloc(16);
  float* XF    = alloc((size_t)BN * 3);
  float* HCAT  = alloc((size_t)BN * 512);
  float* DISTB = alloc((size_t)BN * 2048);   // DIST during knn; then UV|HMAX|HMIN|H1024
  float* UV    = DISTB;                       // BN*512
  float* HMAX  = DISTB + (size_t)BN * 512;    // BN*256
  float* HMIN  = DISTB + (size_t)BN * 768;    // BN*256
  float* H1024 = DISTB + (size_t)BN * 1024;   // BN*1024
  float* SQB   = alloc(BN);
  float* WCOMB = alloc((size_t)512 * 128);
  float* PART  = alloc((size_t)BN * 8);
  float* ST4   = alloc(64);
  float* ST16  = alloc(512);
  float* PQST  = alloc((size_t)8 * 16 * 1024 * 4);
  float* MAXV  = alloc(8 * 1024);
  float* MINV  = alloc(8 * 1024);
  float* GVEC  = alloc(8 * 1024);
  int*   IDX = (int*)alloc((size_t)BN * KNN);
  __hip_bfloat16* HCATBF = (__hip_bfloat16*)alloc((size_t)BN * 256);  // BN*512 bf16
  __hip_bfloat16* WMBF   = (__hip_bfloat16*)alloc(262144);            // 1024*512 bf16

  // converted fp32 weights
  ConvTable ct;
  float* conv_dst[30];
  for (int i = 0; i < 30; ++i) {
    int n = in_sizes[i];
    conv_dst[i] = alloc((size_t)((n + 15) & ~15));
    ct.src[i] = d_in[i];
    ct.dst[i] = conv_dst[i];
    ct.n[i] = n;
  }
  ct.dst[0] = XF; ct.n[0] = BN * 3;

  const float* W_[4]  = {conv_dst[1], conv_dst[4], conv_dst[7], conv_dst[10]};
  const float* GW_[4] = {conv_dst[2], conv_dst[5], conv_dst[8], conv_dst[11]};
  const float* GB_[4] = {conv_dst[3], conv_dst[6], conv_dst[9], conv_dst[12]};
  const float* WM = conv_dst[13];
  const float* GMW = conv_dst[14], *GMB = conv_dst[15];
  const float* FC1W = conv_dst[16], *FC1B = conv_dst[17], *LN1W = conv_dst[18], *LN1B = conv_dst[19];
  const float* FC2W = conv_dst[20], *FC2B = conv_dst[21], *LN2W = conv_dst[22], *LN2B = conv_dst[23];
  const float* FC3W = conv_dst[24], *FC3B = conv_dst[25], *LN3W = conv_dst[26], *LN3B = conv_dst[27];
  const float* FC4W = conv_dst[28], *FC4B = conv_dst[29];

  detect_dtype<<<dim3(1), 64, 0, stream>>>((const unsigned short*)d_in[0], FLAG);
  conv_all<<<dim3(256, 30), 256, 0, stream>>>(ct, FLAG);
  convf2b<<<dim3(2048), 256, 0, stream>>>(WM, WMBF, 1024 * 512);

  const int Cs[4]     = {3, 64, 64, 128};
  const int Os[4]     = {64, 64, 128, 256};
  const int incol[4]  = {0, 0, 64, 128};
  const int outcol[4] = {0, 64, 128, 256};

  for (int l = 0; l < 4; ++l) {
    const int C = Cs[l], O = Os[l], twoO = 2 * O;
    const float* xin = (l == 0) ? XF : (HCAT + incol[l]);
    const int ldx = (l == 0) ? 3 : 512;

    launch_sq(C, xin, ldx, SQB, BN, stream);
    if (l == 0)
      dist_gemm<<<dim3(N / 64, N / 64, B), 256, 0, stream>>>(xin, ldx, SQB, DISTB, N, C);
    else
      dist_gemm128<<<dim3(N / 128, N / 128, B), 256, 0, stream>>>(xin, SQB, DISTB, N, C);
    knn_select<<<dim3(BN / 4), 256, 0, stream>>>(DISTB, IDX, KNN);
    wcomb_build<<<dim3((O * C + 255) / 256), 256, 0, stream>>>(W_[l], WCOMB, O, C);
    gemm_abt<<<dim3(twoO / 64, BN / 64), 256, 0, stream>>>(xin, ldx, WCOMB, UV, twoO, BN, twoO, C);
    edge_pass1<<<dim3(N, B), O, 0, stream>>>(UV, IDX, HMAX, HMIN, PART, N, O);
    stats_reduce<<<dim3(4, B), 256, 0, stream>>>(PART, ST4, N);
    int tot = BN * O;
    edge_pass2<<<dim3((tot + 255) / 256), 256, 0, stream>>>(HMAX, HMIN, ST4, GW_[l], GB_[l],
                                                            HCAT, HCATBF, N, O, KNN, outcol[l], tot);
  }

  gemm_mfma_bt<<<dim3(1024 / 128, BN / 128), 256, 0, stream>>>(HCATBF, WMBF, H1024, 1024, BN, 1024, 512);
  seq_part<<<dim3(4, 8, 16), 256, 0, stream>>>(H1024, (float4*)PQST, N);
  seq_fin<<<dim3(4, 8), 256, 0, stream>>>((const float4*)PQST, ST16, MAXV, MINV);
  seq_apply<<<dim3(32), 256, 0, stream>>>(ST16, MAXV, MINV, GMW, GMB, GVEC, N);

  mlp_head<<<dim3(8), 256, 0, stream>>>(GVEC, FC1W, FC1B, LN1W, LN1B,
                                        FC2W, FC2B, LN2W, LN2B,
                                        FC3W, FC3B, LN3W, LN3B,
                                        FC4W, FC4B, d_out, FLAG);
}